// Round 2
// baseline (523.633 us; speedup 1.0000x reference)
//
#include <hip/hip_runtime.h>
#include <cstdint>

typedef __attribute__((ext_vector_type(8))) __bf16 bf16x8;
typedef __attribute__((ext_vector_type(4))) __bf16 bf16x4;
typedef __attribute__((ext_vector_type(4))) float f32x4;

#define MFMA16(a, b, c) __builtin_amdgcn_mfma_f32_16x16x32_bf16((a), (b), (c), 0, 0, 0)
// counted waitcnt (used by k_flash): NEVER drain vmcnt(0) in the main loop (T4).
#define WAITV(N) asm volatile("s_waitcnt vmcnt(" #N ")" ::: "memory")

static constexpr int SEQ = 2048;
static constexpr int DV = 256;
static constexpr float QK_SCALE = 4.5f;  // qk / INV_SCALE, INV_SCALE = 1/(0.5*9)

__device__ __forceinline__ bf16x4 cvt4(float4 v) {
    bf16x4 y;
    y[0] = (__bf16)v.x; y[1] = (__bf16)v.y; y[2] = (__bf16)v.z; y[3] = (__bf16)v.w;
    return y;
}

// async global->LDS DMA, 16B per lane; LDS dest must be wave-uniform base,
// lane i lands at base + i*16 (no padding possible -> use source-side XOR swizzle)
__device__ __forceinline__ void gl_lds16(const void* g, void* l) {
    __builtin_amdgcn_global_load_lds((const __attribute__((address_space(1))) uint32_t*)g,
                                     (__attribute__((address_space(3))) uint32_t*)l, 16, 0, 0);
}

// ---------------------------------------------------------------------------
// Projection GEMM (unchanged — known correct)
// ---------------------------------------------------------------------------
template <int K, int TRANS>
__global__ __launch_bounds__(256) void k_proj(const float* __restrict__ X,
                                              const float* __restrict__ W,
                                              __bf16* __restrict__ out,
                                              float outScale) {
    __shared__ __bf16 ldsX[64][136];
    __shared__ __bf16 ldsW[128][136];

    const int t = threadIdx.x;
    const int m0 = blockIdx.x * 64;
    const int w = t >> 6, l = t & 63, lrow = l & 15, lq = l >> 4;

    f32x4 acc[8];
#pragma unroll
    for (int i = 0; i < 8; ++i) acc[i] = f32x4{0.f, 0.f, 0.f, 0.f};

#pragma unroll
    for (int kh = 0; kh < K / 128; ++kh) {
        if (kh) __syncthreads();
#pragma unroll
        for (int i = 0; i < 8; ++i) {
            int idx = t + i * 256;
            int r = idx >> 5, c4 = idx & 31;
            float4 v = *(const float4*)(X + (size_t)(m0 + r) * K + kh * 128 + c4 * 4);
            *(bf16x4*)&ldsX[r][c4 * 4] = cvt4(v);
        }
#pragma unroll
        for (int i = 0; i < 16; ++i) {
            int idx = t + i * 256;
            int r = idx >> 5, c4 = idx & 31;
            float4 v = *(const float4*)(W + (size_t)r * K + kh * 128 + c4 * 4);
            *(bf16x4*)&ldsW[r][c4 * 4] = cvt4(v);
        }
        __syncthreads();

        bf16x8 aA[4];
#pragma unroll
        for (int kc = 0; kc < 4; ++kc)
            aA[kc] = *(const bf16x8*)((const char*)&ldsX[w * 16 + lrow][0] + kc * 64 + lq * 16);
#pragma unroll
        for (int nt = 0; nt < 8; ++nt) {
#pragma unroll
            for (int kc = 0; kc < 4; ++kc) {
                bf16x8 bB = *(const bf16x8*)((const char*)&ldsW[nt * 16 + lrow][0] + kc * 64 + lq * 16);
                acc[nt] = MFMA16(aA[kc], bB, acc[nt]);
            }
        }
    }

#pragma unroll
    for (int nt = 0; nt < 8; ++nt) {
#pragma unroll
        for (int j = 0; j < 4; ++j) {
            int gm = m0 + w * 16 + lq * 4 + j;
            int col = nt * 16 + lrow;
            float v = acc[nt][j] * outScale;
            if (TRANS) {
                int b = gm >> 11, s = gm & 2047;
                out[((size_t)b * 128 + col) * SEQ + s] = (__bf16)v;
            } else {
                out[(size_t)gm * 128 + col] = (__bf16)v;
            }
        }
    }
}

// ---------------------------------------------------------------------------
// value [8][2048][256] fp32 -> vt [8][256][2048] bf16 (unchanged)
// ---------------------------------------------------------------------------
__global__ __launch_bounds__(256) void k_vt(const float* __restrict__ V, __bf16* __restrict__ vt) {
    __shared__ __bf16 tile[64][72];
    const int t = threadIdx.x;
    const int b = blockIdx.z, s0 = blockIdx.x * 64, v0 = blockIdx.y * 64;
#pragma unroll
    for (int i = 0; i < 4; ++i) {
        int idx = t + i * 256;
        int r = idx >> 4, c4 = idx & 15;
        float4 x = *(const float4*)(V + ((size_t)b * SEQ + s0 + r) * DV + v0 + c4 * 4);
        *(bf16x4*)&tile[r][c4 * 4] = cvt4(x);
    }
    __syncthreads();
#pragma unroll
    for (int i = 0; i < 4; ++i) {
        int idx = t + i * 256;
        int v = idx >> 4, c4 = idx & 15;
        bf16x4 y;
        y[0] = tile[c4 * 4 + 0][v]; y[1] = tile[c4 * 4 + 1][v];
        y[2] = tile[c4 * 4 + 2][v]; y[3] = tile[c4 * 4 + 3][v];
        *(bf16x4*)(vt + ((size_t)b * DV + v0 + v) * SEQ + s0 + c4 * 4) = y;
    }
}

__global__ __launch_bounds__(256) void k_cvt_bf16(const float* __restrict__ src,
                                                  __bf16* __restrict__ dst, int n4) {
    int i = blockIdx.x * 256 + threadIdx.x;
    if (i < n4) {
        float4 v = *(const float4*)(src + (size_t)i * 4);
        *(bf16x4*)(dst + (size_t)i * 4) = cvt4(v);
    }
}

// ---------------------------------------------------------------------------
// Flash attention (unchanged from round 1 — known correct; pivot next round)
// ---------------------------------------------------------------------------
__global__ __launch_bounds__(256) void k_flash(const __bf16* __restrict__ r1s,
                                               const __bf16* __restrict__ r2,
                                               const __bf16* __restrict__ r3t,
                                               __bf16* __restrict__ v1) {
    __shared__ __align__(16) __bf16 r2s[4][32 * 128];   // [kcol][d] rows 256B, s(r)=r&15
    __shared__ __align__(16) __bf16 r3s[4][128 * 32];   // [o][k]   rows  64B, s(r)=(r>>1)&3
    __shared__ __bf16 plds[4][16][48];                  // P C->A round-trip (wave-local)

    const int t = threadIdx.x;
    const int bx = (int)((blockIdx.x & 7) * 32 + (blockIdx.x >> 3));  // XCD k <-> batch k
    const int b = bx >> 5, q0 = (bx & 31) * 64;
    const int w = t >> 6, l = t & 63, lrow = l & 15, lq = l >> 4;

    const __bf16* r1b = r1s + (size_t)b * SEQ * 128;
    const __bf16* r2b = r2 + (size_t)b * SEQ * 128;
    const __bf16* r3b = r3t + (size_t)b * 128 * SEQ;

    bf16x8 aQ[4];
    {
        const __bf16* p = r1b + (size_t)(q0 + w * 16 + lrow) * 128 + lq * 8;
#pragma unroll
        for (int kc = 0; kc < 4; ++kc) aQ[kc] = *(const bf16x8*)(p + kc * 32);
    }

    // per-lane DMA source pointers (2 r2 issues + 2 r3 issues per wave)
    const __bf16* p_r2[2];
    const __bf16* p_r3[2];
#pragma unroll
    for (int q1 = 0; q1 < 2; ++q1) {
        int r = 8 * w + 4 * q1 + (l >> 4);           // r2 tile row (kcol), 4 rows/issue
        int c = (l & 15) ^ (r & 15);
        p_r2[q1] = r2b + (size_t)r * 128 + c * 8;
        int r3 = 16 * (2 * w + q1) + (l >> 2);       // r3 tile row (o), 16 rows/issue
        int c3 = (l & 3) ^ ((r3 >> 1) & 3);
        p_r3[q1] = r3b + (size_t)r3 * SEQ + c3 * 8;
    }

    auto stage = [&](int bi) {
#pragma unroll
        for (int q1 = 0; q1 < 2; ++q1) {
            gl_lds16(p_r2[q1], &r2s[bi][(2 * w + q1) * 512]);
            gl_lds16(p_r3[q1], &r3s[bi][(2 * w + q1) * 512]);
            p_r2[q1] += 32 * 128;   // next k-tile: 32 kcol rows
            p_r3[q1] += 32;         // next k-window
        }
    };

    f32x4 acc[8];
#pragma unroll
    for (int i = 0; i < 8; ++i) acc[i] = f32x4{0.f, 0.f, 0.f, 0.f};
    float mrow[4] = {-INFINITY, -INFINITY, -INFINITY, -INFINITY};
    float lsum[4] = {0.f, 0.f, 0.f, 0.f};

    stage(0); stage(1); stage(2);          // 12 DMA instrs in flight
    for (int it = 0; it < 64; ++it) {
        // retire stage(it): stages it+1, it+2 stay in flight (8 instrs).
        if (it < 62) { WAITV(8); } else if (it == 62) { WAITV(4); } else { WAITV(0); }
        __builtin_amdgcn_s_barrier();          // all waves' DMA for tile it landed
        __builtin_amdgcn_sched_barrier(0);
        if (it + 3 < 64) stage((it + 3) & 3);  // buffer (it-1)&3: reads done pre-barrier
        __builtin_amdgcn_sched_barrier(0);
        const __bf16* R2 = &r2s[it & 3][0];
        const __bf16* R3 = &r3s[it & 3][0];

        // S = r1 . r2^T  (16q x 32k per wave)
        f32x4 sc[2];
#pragma unroll
        for (int ct = 0; ct < 2; ++ct) {
            f32x4 s = f32x4{0.f, 0.f, 0.f, 0.f};
#pragma unroll
            for (int kc = 0; kc < 4; ++kc) {
                int p = (kc * 4 + lq) ^ lrow;
                bf16x8 bb = *(const bf16x8*)&R2[(ct * 16 + lrow) * 128 + p * 8];
                s = MFMA16(aQ[kc], bb, s);
            }
            sc[ct] = s;
        }

        // online softmax (rows in lanes sharing lq)
        float pm[4], ps[4], al[4];
#pragma unroll
        for (int j = 0; j < 4; ++j) pm[j] = fmaxf(sc[0][j], sc[1][j]);
#pragma unroll
        for (int off = 1; off <= 8; off <<= 1)
#pragma unroll
            for (int j = 0; j < 4; ++j) pm[j] = fmaxf(pm[j], __shfl_xor(pm[j], off, 64));
#pragma unroll
        for (int j = 0; j < 4; ++j) {
            float mn = fmaxf(mrow[j], pm[j]);
            al[j] = __expf(mrow[j] - mn);
            mrow[j] = mn;
            ps[j] = 0.f;
        }
        float pr[2][4];
#pragma unroll
        for (int ct = 0; ct < 2; ++ct)
#pragma unroll
            for (int j = 0; j < 4; ++j) {
                float p = __expf(sc[ct][j] - mrow[j]);
                pr[ct][j] = p;
                ps[j] += p;
            }
#pragma unroll
        for (int off = 1; off <= 8; off <<= 1)
#pragma unroll
            for (int j = 0; j < 4; ++j) ps[j] += __shfl_xor(ps[j], off, 64);
#pragma unroll
        for (int j = 0; j < 4; ++j) lsum[j] = lsum[j] * al[j] + ps[j];
#pragma unroll
        for (int ot = 0; ot < 8; ++ot)
#pragma unroll
            for (int j = 0; j < 4; ++j) acc[ot][j] *= al[j];

        // P: C-layout -> LDS -> A-layout (wave-local; LDS ops in-order per wave)
#pragma unroll
        for (int ct = 0; ct < 2; ++ct)
#pragma unroll
            for (int j = 0; j < 4; ++j)
                plds[w][lq * 4 + j][ct * 16 + lrow] = (__bf16)pr[ct][j];
        __builtin_amdgcn_s_waitcnt(0xc07f);  // lgkmcnt(0) only — DMA stays in flight
        bf16x8 pA = *(const bf16x8*)&plds[w][lrow][lq * 8];

#pragma unroll
        for (int ot = 0; ot < 8; ++ot) {
            int p = lq ^ ((lrow >> 1) & 3);
            bf16x8 bb = *(const bf16x8*)&R3[(ot * 16 + lrow) * 32 + p * 8];
            acc[ot] = MFMA16(pA, bb, acc[ot]);
        }
    }

#pragma unroll
    for (int ot = 0; ot < 8; ++ot)
#pragma unroll
        for (int j = 0; j < 4; ++j) {
            int q = q0 + w * 16 + lq * 4 + j;
            float v = acc[ot][j] / lsum[j];
            v1[((size_t)b * SEQ + q) * 128 + ot * 16 + lrow] = (__bf16)v;
        }
}

// ---------------------------------------------------------------------------
// out = mask@value + (P@r3)@Wout^T.  v4: barrier-free, LDS-free. BM=16,
// grid 1024 -> 4 wg/CU = 16 waves/CU (2x occupancy). Operands loaded directly
// into MFMA fragments from global (vt is L2-resident per XCD; mask is an HBM
// stream whose 4x intra-wg redundancy hits L1 — drift bounded by a barrier
// every 8 iters). Register double-buffer; compiler emits counted vmcnt.
// ---------------------------------------------------------------------------
__global__ __launch_bounds__(256, 4) void k_out(const float* __restrict__ mask,
                                                const __bf16* __restrict__ vtb,
                                                const __bf16* __restrict__ v1,
                                                const __bf16* __restrict__ wob,
                                                float* __restrict__ out) {
    const int t = threadIdx.x;
    const int bid = (int)((blockIdx.x & 7) * 128 + (blockIdx.x >> 3));  // batch<->XCD
    const int m0 = bid * 16;                  // global q-row (b*2048 + q)
    const int b = m0 >> 11;
    const int w = t >> 6, l = t & 63, lrow = l & 15, lq = l >> 4;

    // A-frag source: mask row q = m0+lrow, k-chunk lq*8 (fp32, 32B/lane/iter)
    const float* mrow = mask + (size_t)(m0 + lrow) * SEQ + lq * 8;
    // B-frag source: vt rows w*64 + vt8*16 + lrow (bf16, 16B/lane/iter each)
    const __bf16* vrow[4];
#pragma unroll
    for (int vt8 = 0; vt8 < 4; ++vt8)
        vrow[vt8] = vtb + ((size_t)b * DV + w * 64 + vt8 * 16 + lrow) * SEQ + lq * 8;

    f32x4 acc[4];
#pragma unroll
    for (int i = 0; i < 4; ++i) acc[i] = f32x4{0.f, 0.f, 0.f, 0.f};

    float4 ma0, ma1, mb0, mb1;
    bf16x8 va[4], vb[4];

    // preload set A (it = 0)
    ma0 = *(const float4*)(mrow);
    ma1 = *(const float4*)(mrow + 4);
#pragma unroll
    for (int vt8 = 0; vt8 < 4; ++vt8) va[vt8] = *(const bf16x8*)(vrow[vt8]);

    for (int it = 0; it < 64; it += 2) {
        // issue set B (it+1) — overlaps compute of A
        {
            int k1 = ((it + 1) & 63) * 32;
            mb0 = *(const float4*)(mrow + k1);
            mb1 = *(const float4*)(mrow + k1 + 4);
#pragma unroll
            for (int vt8 = 0; vt8 < 4; ++vt8) vb[vt8] = *(const bf16x8*)(vrow[vt8] + k1);
        }
        {   // compute A
            bf16x8 aM;
            aM[0] = (__bf16)ma0.x; aM[1] = (__bf16)ma0.y; aM[2] = (__bf16)ma0.z; aM[3] = (__bf16)ma0.w;
            aM[4] = (__bf16)ma1.x; aM[5] = (__bf16)ma1.y; aM[6] = (__bf16)ma1.z; aM[7] = (__bf16)ma1.w;
#pragma unroll
            for (int vt8 = 0; vt8 < 4; ++vt8) acc[vt8] = MFMA16(aM, va[vt8], acc[vt8]);
        }
        // issue set A (it+2)
        {
            int k2 = ((it + 2) & 63) * 32;
            ma0 = *(const float4*)(mrow + k2);
            ma1 = *(const float4*)(mrow + k2 + 4);
#pragma unroll
            for (int vt8 = 0; vt8 < 4; ++vt8) va[vt8] = *(const bf16x8*)(vrow[vt8] + k2);
        }
        {   // compute B
            bf16x8 aM;
            aM[0] = (__bf16)mb0.x; aM[1] = (__bf16)mb0.y; aM[2] = (__bf16)mb0.z; aM[3] = (__bf16)mb0.w;
            aM[4] = (__bf16)mb1.x; aM[5] = (__bf16)mb1.y; aM[6] = (__bf16)mb1.z; aM[7] = (__bf16)mb1.w;
#pragma unroll
            for (int vt8 = 0; vt8 < 4; ++vt8) acc[vt8] = MFMA16(aM, vb[vt8], acc[vt8]);
        }
        // bound wave drift so the 4 waves' shared mask lines stay L1/L2-hot
        if ((it & 7) == 6) __builtin_amdgcn_s_barrier();
    }

    // epilogue: + v1 @ Wout^T (small, direct from global/L2)
    bf16x8 aV[4];
#pragma unroll
    for (int oc = 0; oc < 4; ++oc)
        aV[oc] = *(const bf16x8*)(v1 + (size_t)(m0 + lrow) * 128 + oc * 32 + lq * 8);
#pragma unroll
    for (int vt8 = 0; vt8 < 4; ++vt8) {
#pragma unroll
        for (int oc = 0; oc < 4; ++oc) {
            bf16x8 bb = *(const bf16x8*)(wob + (size_t)(w * 64 + vt8 * 16 + lrow) * 128 + oc * 32 + lq * 8);
            acc[vt8] = MFMA16(aV[oc], bb, acc[vt8]);
        }
    }

#pragma unroll
    for (int vt8 = 0; vt8 < 4; ++vt8)
#pragma unroll
        for (int j = 0; j < 4; ++j) {
            int gq = m0 + lq * 4 + j;
            out[(size_t)gq * 256 + w * 64 + vt8 * 16 + lrow] = acc[vt8][j];
        }
}

// ---------------------------------------------------------------------------
extern "C" void kernel_launch(void* const* d_in, const int* in_sizes, int n_in,
                              void* d_out, int out_size, void* d_ws, size_t ws_size,
                              hipStream_t stream) {
    const float* q    = (const float*)d_in[0];
    const float* k    = (const float*)d_in[1];
    const float* v    = (const float*)d_in[2];
    const float* mask = (const float*)d_in[3];
    const float* W0   = (const float*)d_in[4];
    const float* W1   = (const float*)d_in[5];
    const float* W2   = (const float*)d_in[6];
    const float* Wout = (const float*)d_in[7];
    float* out = (float*)d_out;

    char* ws = (char*)d_ws;
    __bf16* r1s = (__bf16*)(ws);                  // [8][2048][128] bf16 (pre-scaled 4.5)
    __bf16* r2b = (__bf16*)(ws + (4ull << 20));   // [8][2048][128] bf16
    __bf16* r3t = (__bf16*)(ws + (8ull << 20));   // [8][128][2048] bf16 (transposed)
    __bf16* vtb = (__bf16*)(ws + (12ull << 20));  // [8][256][2048] bf16 (transposed)
    __bf16* wob = (__bf16*)(ws + (20ull << 20));  // [256][128] bf16
    __bf16* v1b = (__bf16*)(ws + (21ull << 20));  // [8][2048][128] bf16

    k_proj<128, 0><<<256, 256, 0, stream>>>(q, W0, r1s, QK_SCALE);
    k_proj<128, 0><<<256, 256, 0, stream>>>(k, W1, r2b, 1.0f);
    k_proj<256, 1><<<256, 256, 0, stream>>>(v, W2, r3t, 1.0f);
    k_vt<<<dim3(32, 4, 8), 256, 0, stream>>>(v, vtb);
    k_cvt_bf16<<<32, 256, 0, stream>>>(Wout, wob, 8192);
    k_flash<<<256, 256, 0, stream>>>(r1s, r2b, r3t, v1b);
    k_out<<<1024, 256, 0, stream>>>(mask, vtb, v1b, wob, out);
}

// Round 3
// 454.990 us; speedup vs baseline: 1.1509x; 1.1509x over previous
//
#include <hip/hip_runtime.h>
#include <cstdint>

typedef __attribute__((ext_vector_type(8))) __bf16 bf16x8;
typedef __attribute__((ext_vector_type(4))) __bf16 bf16x4;
typedef __attribute__((ext_vector_type(4))) float f32x4;

#define MFMA16(a, b, c) __builtin_amdgcn_mfma_f32_16x16x32_bf16((a), (b), (c), 0, 0, 0)
// counted waitcnt (k_flash): NEVER drain vmcnt(0) in the main loop (T4).
#define WAITV(N) asm volatile("s_waitcnt vmcnt(" #N ")" ::: "memory")

static constexpr int SEQ = 2048;
static constexpr int DV = 256;
static constexpr float QK_SCALE = 4.5f;  // qk / INV_SCALE, INV_SCALE = 1/(0.5*9)

__device__ __forceinline__ bf16x4 cvt4(float4 v) {
    bf16x4 y;
    y[0] = (__bf16)v.x; y[1] = (__bf16)v.y; y[2] = (__bf16)v.z; y[3] = (__bf16)v.w;
    return y;
}

// async global->LDS DMA, 16B per lane; LDS dest wave-uniform base + lane*16.
__device__ __forceinline__ void gl_lds16(const void* g, void* l) {
    __builtin_amdgcn_global_load_lds((const __attribute__((address_space(1))) uint32_t*)g,
                                     (__attribute__((address_space(3))) uint32_t*)l, 16, 0, 0);
}

// ---------------------------------------------------------------------------
// Projection GEMM. TRANS=1 now writes r3 PACKED: [b][kt=64][o=128][k=32] bf16
// with chunk-XOR baked (slot = (k>>3) ^ ((o>>1)&3)) so k_flash's r3 DMA reads
// are 1 KB fully contiguous and its LDS read code is unchanged.
// ---------------------------------------------------------------------------
template <int K, int TRANS>
__global__ __launch_bounds__(256) void k_proj(const float* __restrict__ X,
                                              const float* __restrict__ W,
                                              __bf16* __restrict__ out,
                                              float outScale) {
    __shared__ __bf16 ldsX[64][136];
    __shared__ __bf16 ldsW[128][136];

    const int t = threadIdx.x;
    const int m0 = blockIdx.x * 64;
    const int w = t >> 6, l = t & 63, lrow = l & 15, lq = l >> 4;

    f32x4 acc[8];
#pragma unroll
    for (int i = 0; i < 8; ++i) acc[i] = f32x4{0.f, 0.f, 0.f, 0.f};

#pragma unroll
    for (int kh = 0; kh < K / 128; ++kh) {
        if (kh) __syncthreads();
#pragma unroll
        for (int i = 0; i < 8; ++i) {
            int idx = t + i * 256;
            int r = idx >> 5, c4 = idx & 31;
            float4 v = *(const float4*)(X + (size_t)(m0 + r) * K + kh * 128 + c4 * 4);
            *(bf16x4*)&ldsX[r][c4 * 4] = cvt4(v);
        }
#pragma unroll
        for (int i = 0; i < 16; ++i) {
            int idx = t + i * 256;
            int r = idx >> 5, c4 = idx & 31;
            float4 v = *(const float4*)(W + (size_t)r * K + kh * 128 + c4 * 4);
            *(bf16x4*)&ldsW[r][c4 * 4] = cvt4(v);
        }
        __syncthreads();

        bf16x8 aA[4];
#pragma unroll
        for (int kc = 0; kc < 4; ++kc)
            aA[kc] = *(const bf16x8*)((const char*)&ldsX[w * 16 + lrow][0] + kc * 64 + lq * 16);
#pragma unroll
        for (int nt = 0; nt < 8; ++nt) {
#pragma unroll
            for (int kc = 0; kc < 4; ++kc) {
                bf16x8 bB = *(const bf16x8*)((const char*)&ldsW[nt * 16 + lrow][0] + kc * 64 + lq * 16);
                acc[nt] = MFMA16(aA[kc], bB, acc[nt]);
            }
        }
    }

#pragma unroll
    for (int nt = 0; nt < 8; ++nt) {
        if (TRANS) {
            // packed r3 store: 4 consecutive s-values (j=0..3) = one bf16x4
            int gm = m0 + w * 16 + lq * 4;       // j = 0 global row
            int b = gm >> 11, s = gm & 2047;
            int col = nt * 16 + lrow;            // o
            int kt = s >> 5, s32 = s & 31;
            int slot = (s32 >> 3) ^ ((col >> 1) & 3);
            bf16x4 y;
#pragma unroll
            for (int j = 0; j < 4; ++j) y[j] = (__bf16)(acc[nt][j] * outScale);
            *(bf16x4*)(out + (((size_t)b * 64 + kt) * 128 + col) * 32 + slot * 8 + (s32 & 7)) = y;
        } else {
#pragma unroll
            for (int j = 0; j < 4; ++j) {
                int gm = m0 + w * 16 + lq * 4 + j;
                int col = nt * 16 + lrow;
                out[(size_t)gm * 128 + col] = (__bf16)(acc[nt][j] * outScale);
            }
        }
    }
}

// ---------------------------------------------------------------------------
// value [8][2048][256] fp32 -> vt PACKED [b][kt=64][v=256][k=32] bf16,
// chunk-XOR baked: slot = ((k>>3) ^ ((v>>1)&3)). Every 32-k tile of all 256
// v-rows is a contiguous 16 KB block -> k_out frag loads are 1 KB contiguous.
// ---------------------------------------------------------------------------
__global__ __launch_bounds__(256) void k_vt(const float* __restrict__ V, __bf16* __restrict__ vt) {
    __shared__ __bf16 tile[64][72];
    const int t = threadIdx.x;
    const int b = blockIdx.z, s0 = blockIdx.x * 64, v0 = blockIdx.y * 64;
#pragma unroll
    for (int i = 0; i < 4; ++i) {
        int idx = t + i * 256;
        int r = idx >> 4, c4 = idx & 15;
        float4 x = *(const float4*)(V + ((size_t)b * SEQ + s0 + r) * DV + v0 + c4 * 4);
        *(bf16x4*)&tile[r][c4 * 4] = cvt4(x);
    }
    __syncthreads();
#pragma unroll
    for (int i = 0; i < 4; ++i) {
        int idx = t + i * 256;
        int vv = idx >> 4, c4 = idx & 15;
        bf16x4 y;
        y[0] = tile[c4 * 4 + 0][vv]; y[1] = tile[c4 * 4 + 1][vv];
        y[2] = tile[c4 * 4 + 2][vv]; y[3] = tile[c4 * 4 + 3][vv];
        int v = v0 + vv;
        int kt = (s0 >> 5) + (c4 >> 3);
        int slot = ((c4 >> 1) & 3) ^ ((v >> 1) & 3);
        *(bf16x4*)(vt + (((size_t)b * 64 + kt) * 256 + v) * 32 + slot * 8 + (c4 & 1) * 4) = y;
    }
}

__global__ __launch_bounds__(256) void k_cvt_bf16(const float* __restrict__ src,
                                                  __bf16* __restrict__ dst, int n4) {
    int i = blockIdx.x * 256 + threadIdx.x;
    if (i < n4) {
        float4 v = *(const float4*)(src + (size_t)i * 4);
        *(bf16x4*)(dst + (size_t)i * 4) = cvt4(v);
    }
}

// ---------------------------------------------------------------------------
// Flash attention: structure unchanged from round 1 EXCEPT r3 now comes from
// the packed layout -> each r3 DMA instr reads 1 KB fully contiguous (was
// 16 rows x 64 B at 4 KB stride). LDS image identical; read code unchanged.
// ---------------------------------------------------------------------------
__global__ __launch_bounds__(256) void k_flash(const __bf16* __restrict__ r1s,
                                               const __bf16* __restrict__ r2,
                                               const __bf16* __restrict__ r3p,
                                               __bf16* __restrict__ v1) {
    __shared__ __align__(16) __bf16 r2s[4][32 * 128];   // [kcol][d] rows 256B, s(r)=r&15
    __shared__ __align__(16) __bf16 r3s[4][128 * 32];   // [o][k]   rows  64B, s(r)=(r>>1)&3
    __shared__ __bf16 plds[4][16][48];                  // P C->A round-trip (wave-local)

    const int t = threadIdx.x;
    const int bx = (int)((blockIdx.x & 7) * 32 + (blockIdx.x >> 3));  // XCD <-> batch
    const int b = bx >> 5, q0 = (bx & 31) * 64;
    const int w = t >> 6, l = t & 63, lrow = l & 15, lq = l >> 4;

    const __bf16* r1b = r1s + (size_t)b * SEQ * 128;
    const __bf16* r2b = r2 + (size_t)b * SEQ * 128;
    const __bf16* r3b = r3p + (size_t)b * 64 * 128 * 32;   // packed [kt][o][k32]

    bf16x8 aQ[4];
    {
        const __bf16* p = r1b + (size_t)(q0 + w * 16 + lrow) * 128 + lq * 8;
#pragma unroll
        for (int kc = 0; kc < 4; ++kc) aQ[kc] = *(const bf16x8*)(p + kc * 32);
    }

    // per-lane DMA source pointers
    const __bf16* p_r2[2];
    const __bf16* p_r3[2];
#pragma unroll
    for (int q1 = 0; q1 < 2; ++q1) {
        int r = 8 * w + 4 * q1 + (l >> 4);           // r2 tile row (kcol), 4 rows/issue
        int c = (l & 15) ^ (r & 15);
        p_r2[q1] = r2b + (size_t)r * 128 + c * 8;
        // r3 packed: issue (2w+q1) covers o-rows 16(2w+q1)..+15 of k-tile kt;
        // contiguous: lane l -> +l*16 B
        p_r3[q1] = r3b + (size_t)(2 * w + q1) * 512 + l * 8;
    }

    auto stage = [&](int bi) {
#pragma unroll
        for (int q1 = 0; q1 < 2; ++q1) {
            gl_lds16(p_r2[q1], &r2s[bi][(2 * w + q1) * 512]);
            gl_lds16(p_r3[q1], &r3s[bi][(2 * w + q1) * 512]);
            p_r2[q1] += 32 * 128;   // next k-tile: 32 kcol rows
            p_r3[q1] += 128 * 32;   // next packed k-tile block
        }
    };

    f32x4 acc[8];
#pragma unroll
    for (int i = 0; i < 8; ++i) acc[i] = f32x4{0.f, 0.f, 0.f, 0.f};
    float mrow[4] = {-INFINITY, -INFINITY, -INFINITY, -INFINITY};
    float lsum[4] = {0.f, 0.f, 0.f, 0.f};

    stage(0); stage(1); stage(2);          // 12 DMA instrs in flight
    for (int it = 0; it < 64; ++it) {
        if (it < 62) { WAITV(8); } else if (it == 62) { WAITV(4); } else { WAITV(0); }
        __builtin_amdgcn_s_barrier();
        __builtin_amdgcn_sched_barrier(0);
        if (it + 3 < 64) stage((it + 3) & 3);
        __builtin_amdgcn_sched_barrier(0);
        const __bf16* R2 = &r2s[it & 3][0];
        const __bf16* R3 = &r3s[it & 3][0];

        // S = r1 . r2^T  (16q x 32k per wave)
        f32x4 sc[2];
#pragma unroll
        for (int ct = 0; ct < 2; ++ct) {
            f32x4 s = f32x4{0.f, 0.f, 0.f, 0.f};
#pragma unroll
            for (int kc = 0; kc < 4; ++kc) {
                int p = (kc * 4 + lq) ^ lrow;
                bf16x8 bb = *(const bf16x8*)&R2[(ct * 16 + lrow) * 128 + p * 8];
                s = MFMA16(aQ[kc], bb, s);
            }
            sc[ct] = s;
        }

        // online softmax
        float pm[4], ps[4], al[4];
#pragma unroll
        for (int j = 0; j < 4; ++j) pm[j] = fmaxf(sc[0][j], sc[1][j]);
#pragma unroll
        for (int off = 1; off <= 8; off <<= 1)
#pragma unroll
            for (int j = 0; j < 4; ++j) pm[j] = fmaxf(pm[j], __shfl_xor(pm[j], off, 64));
#pragma unroll
        for (int j = 0; j < 4; ++j) {
            float mn = fmaxf(mrow[j], pm[j]);
            al[j] = __expf(mrow[j] - mn);
            mrow[j] = mn;
            ps[j] = 0.f;
        }
        float pr[2][4];
#pragma unroll
        for (int ct = 0; ct < 2; ++ct)
#pragma unroll
            for (int j = 0; j < 4; ++j) {
                float p = __expf(sc[ct][j] - mrow[j]);
                pr[ct][j] = p;
                ps[j] += p;
            }
#pragma unroll
        for (int off = 1; off <= 8; off <<= 1)
#pragma unroll
            for (int j = 0; j < 4; ++j) ps[j] += __shfl_xor(ps[j], off, 64);
#pragma unroll
        for (int j = 0; j < 4; ++j) lsum[j] = lsum[j] * al[j] + ps[j];
#pragma unroll
        for (int ot = 0; ot < 8; ++ot)
#pragma unroll
            for (int j = 0; j < 4; ++j) acc[ot][j] *= al[j];

        // P: C-layout -> LDS -> A-layout (wave-local)
#pragma unroll
        for (int ct = 0; ct < 2; ++ct)
#pragma unroll
            for (int j = 0; j < 4; ++j)
                plds[w][lq * 4 + j][ct * 16 + lrow] = (__bf16)pr[ct][j];
        __builtin_amdgcn_s_waitcnt(0xc07f);  // lgkmcnt(0) only — DMA stays in flight
        bf16x8 pA = *(const bf16x8*)&plds[w][lrow][lq * 8];

#pragma unroll
        for (int ot = 0; ot < 8; ++ot) {
            int p = lq ^ ((lrow >> 1) & 3);
            bf16x8 bb = *(const bf16x8*)&R3[(ot * 16 + lrow) * 32 + p * 8];
            acc[ot] = MFMA16(pA, bb, acc[ot]);
        }
    }

#pragma unroll
    for (int ot = 0; ot < 8; ++ot)
#pragma unroll
        for (int j = 0; j < 4; ++j) {
            int q = q0 + w * 16 + lq * 4 + j;
            float v = acc[ot][j] / lsum[j];
            v1[((size_t)b * SEQ + q) * 128 + ot * 16 + lrow] = (__bf16)v;
        }
}

// ---------------------------------------------------------------------------
// out = mask@value + (P@r3)@Wout^T.  v5: DRAM-run-length fix.
// BM=32, BN=256, BK=256, 8 iters, grid 512 (2 wg/CU), 4 waves.
// mask: T14 reg-staged, ONE FULL ROW (1 KB contiguous) per load instr;
//       LDS mbuf[2][32][256] fp32 with 16B-chunk XOR (slot = c ^ (row&7)).
// vt:   packed [b][kt][v][k32] read DIRECTLY to regs, 1 KB contiguous per
//       frag-load, L2-resident (XCD = one batch). No DMA -> no vmcnt mixing.
// ---------------------------------------------------------------------------
__global__ __launch_bounds__(256) void k_out(const float* __restrict__ mask,
                                             const __bf16* __restrict__ vtp,
                                             const __bf16* __restrict__ v1,
                                             const __bf16* __restrict__ wob,
                                             float* __restrict__ out) {
    __shared__ __align__(16) float mbuf[2][32 * 256];   // 64 KB

    const int t = threadIdx.x;
    const int bid = (int)((blockIdx.x & 7) * 64 + (blockIdx.x >> 3));  // XCD = batch
    const int m0 = bid * 32;
    const int b = m0 >> 11, q0 = m0 & 2047;
    const int w = t >> 6, l = t & 63, lrow = l & 15, lq = l >> 4;
    const int rg = w & 1, ch = w >> 1;   // wave -> 16-row group x 128-col half

    f32x4 acc[8];
#pragma unroll
    for (int i = 0; i < 8; ++i) acc[i] = f32x4{0.f, 0.f, 0.f, 0.f};

    const float* mbase = mask + ((size_t)b * SEQ + q0) * SEQ;
    // vt frag base: frag (kt, vt8) at vbase + kt*8192 + vt8*512 (elems)
    const int pv = lq ^ ((lrow >> 1) & 3);
    const __bf16* vbase = vtp + ((size_t)b * 64 * 256 + (size_t)(ch * 128 + lrow)) * 32 + pv * 8;

    float4 mr[8];
    // prologue: load + write iter-0 mask tile (rows w*8..w*8+7, full 1 KB rows)
    {
        const float* pm = mbase + (size_t)(w * 8) * SEQ + l * 4;
#pragma unroll
        for (int i = 0; i < 8; ++i) mr[i] = *(const float4*)(pm + (size_t)i * SEQ);
#pragma unroll
        for (int i = 0; i < 8; ++i)
            *(float4*)&mbuf[0][(w * 8 + i) * 256 + ((l ^ i) * 4)] = mr[i];
    }
    __syncthreads();

    bf16x8 vreg[2][8];
    // preload vt k-step 0 (kt = 0)
#pragma unroll
    for (int f = 0; f < 8; ++f) vreg[0][f] = *(const bf16x8*)(vbase + (size_t)f * 512);

    for (int it = 0; it < 8; ++it) {
        const float* Mb = &mbuf[it & 1][0] + (size_t)(rg * 16 + lrow) * 256;
        const int ktb = it * 8;
#pragma unroll
        for (int ks = 0; ks < 8; ++ks) {
            // prefetch next k-step's vt frags (1 KB contiguous each)
            if (ktb + ks + 1 < 64) {
                const __bf16* p = vbase + (size_t)(ktb + ks + 1) * 8192;
#pragma unroll
                for (int f = 0; f < 8; ++f) vreg[(ks + 1) & 1][f] = *(const bf16x8*)(p + (size_t)f * 512);
            }
            // issue next iter's mask rows late (keeps vt reg-load waits unblocked)
            if (ks == 6 && it + 1 < 8) {
                const float* pm = mbase + (size_t)(w * 8) * SEQ + (it + 1) * 256 + l * 4;
#pragma unroll
                for (int i = 0; i < 8; ++i) mr[i] = *(const float4*)(pm + (size_t)i * SEQ);
            }
            // A-frag: mask fp32 -> bf16 (chunks ks*8+lq*2, +1, XOR (lrow&7))
            float4 f0 = *(const float4*)(Mb + (((ks * 8 + lq * 2) ^ (lrow & 7)) << 2));
            float4 f1 = *(const float4*)(Mb + (((ks * 8 + lq * 2 + 1) ^ (lrow & 7)) << 2));
            bf16x8 aM;
            aM[0] = (__bf16)f0.x; aM[1] = (__bf16)f0.y; aM[2] = (__bf16)f0.z; aM[3] = (__bf16)f0.w;
            aM[4] = (__bf16)f1.x; aM[5] = (__bf16)f1.y; aM[6] = (__bf16)f1.z; aM[7] = (__bf16)f1.w;
#pragma unroll
            for (int f = 0; f < 8; ++f) acc[f] = MFMA16(aM, vreg[ks & 1][f], acc[f]);
        }
        if (it + 1 < 8) {
            __syncthreads();   // all waves done reading mbuf[(it+1)&1] (read 2 iters ago)
#pragma unroll
            for (int i = 0; i < 8; ++i)
                *(float4*)&mbuf[(it + 1) & 1][(w * 8 + i) * 256 + ((l ^ i) * 4)] = mr[i];
            __syncthreads();
        }
    }

    // epilogue: + v1 @ Wout^T (small, direct from global/L2)
    bf16x8 aV[4];
#pragma unroll
    for (int oc = 0; oc < 4; ++oc)
        aV[oc] = *(const bf16x8*)(v1 + (size_t)(m0 + rg * 16 + lrow) * 128 + oc * 32 + lq * 8);
#pragma unroll
    for (int vt8 = 0; vt8 < 8; ++vt8) {
#pragma unroll
        for (int oc = 0; oc < 4; ++oc) {
            bf16x8 bb = *(const bf16x8*)(wob + (size_t)(ch * 128 + vt8 * 16 + lrow) * 128 + oc * 32 + lq * 8);
            acc[vt8] = MFMA16(aV[oc], bb, acc[vt8]);
        }
    }

#pragma unroll
    for (int vt8 = 0; vt8 < 8; ++vt8)
#pragma unroll
        for (int j = 0; j < 4; ++j) {
            int gq = m0 + rg * 16 + lq * 4 + j;
            out[(size_t)gq * 256 + ch * 128 + vt8 * 16 + lrow] = acc[vt8][j];
        }
}

// ---------------------------------------------------------------------------
extern "C" void kernel_launch(void* const* d_in, const int* in_sizes, int n_in,
                              void* d_out, int out_size, void* d_ws, size_t ws_size,
                              hipStream_t stream) {
    const float* q    = (const float*)d_in[0];
    const float* k    = (const float*)d_in[1];
    const float* v    = (const float*)d_in[2];
    const float* mask = (const float*)d_in[3];
    const float* W0   = (const float*)d_in[4];
    const float* W1   = (const float*)d_in[5];
    const float* W2   = (const float*)d_in[6];
    const float* Wout = (const float*)d_in[7];
    float* out = (float*)d_out;

    char* ws = (char*)d_ws;
    __bf16* r1s = (__bf16*)(ws);                  // [8][2048][128] bf16 (pre-scaled 4.5)
    __bf16* r2b = (__bf16*)(ws + (4ull << 20));   // [8][2048][128] bf16
    __bf16* r3t = (__bf16*)(ws + (8ull << 20));   // [8][64][128][32] bf16 PACKED
    __bf16* vtb = (__bf16*)(ws + (12ull << 20));  // [8][64][256][32] bf16 PACKED
    __bf16* wob = (__bf16*)(ws + (20ull << 20));  // [256][128] bf16
    __bf16* v1b = (__bf16*)(ws + (21ull << 20));  // [8][2048][128] bf16

    k_proj<128, 0><<<256, 256, 0, stream>>>(q, W0, r1s, QK_SCALE);
    k_proj<128, 0><<<256, 256, 0, stream>>>(k, W1, r2b, 1.0f);
    k_proj<256, 1><<<256, 256, 0, stream>>>(v, W2, r3t, 1.0f);
    k_vt<<<dim3(32, 4, 8), 256, 0, stream>>>(v, vtb);
    k_cvt_bf16<<<32, 256, 0, stream>>>(Wout, wob, 8192);
    k_flash<<<256, 256, 0, stream>>>(r1s, r2b, r3t, v1b);
    k_out<<<512, 256, 0, stream>>>(mask, vtb, v1b, wob, out);
}

// Round 4
// 392.997 us; speedup vs baseline: 1.3324x; 1.1577x over previous
//
#include <hip/hip_runtime.h>
#include <cstdint>

typedef __attribute__((ext_vector_type(8))) __bf16 bf16x8;
typedef __attribute__((ext_vector_type(4))) __bf16 bf16x4;
typedef __attribute__((ext_vector_type(4))) float f32x4;

#define MFMA16(a, b, c) __builtin_amdgcn_mfma_f32_16x16x32_bf16((a), (b), (c), 0, 0, 0)
// counted waitcnt: NEVER drain vmcnt(0) in the main loop (T4).
#define WAITV(N) asm volatile("s_waitcnt vmcnt(" #N ")" ::: "memory")

static constexpr int SEQ = 2048;
static constexpr int DV = 256;
static constexpr float QK_SCALE = 4.5f;  // qk / INV_SCALE, INV_SCALE = 1/(0.5*9)

__device__ __forceinline__ bf16x4 cvt4(float4 v) {
    bf16x4 y;
    y[0] = (__bf16)v.x; y[1] = (__bf16)v.y; y[2] = (__bf16)v.z; y[3] = (__bf16)v.w;
    return y;
}

// async global->LDS DMA, 16B per lane; LDS dest wave-uniform base + lane*16.
__device__ __forceinline__ void gl_lds16(const void* g, void* l) {
    __builtin_amdgcn_global_load_lds((const __attribute__((address_space(1))) uint32_t*)g,
                                     (__attribute__((address_space(3))) uint32_t*)l, 16, 0, 0);
}

// ---------------------------------------------------------------------------
// Projection GEMM. TRANS=1 writes r3 PACKED: [b][kt=64][o=128][k=32] bf16
// with chunk-XOR baked (slot = (k>>3) ^ ((o>>1)&3)).
// ---------------------------------------------------------------------------
template <int K, int TRANS>
__global__ __launch_bounds__(256) void k_proj(const float* __restrict__ X,
                                              const float* __restrict__ W,
                                              __bf16* __restrict__ out,
                                              float outScale) {
    __shared__ __bf16 ldsX[64][136];
    __shared__ __bf16 ldsW[128][136];

    const int t = threadIdx.x;
    const int m0 = blockIdx.x * 64;
    const int w = t >> 6, l = t & 63, lrow = l & 15, lq = l >> 4;

    f32x4 acc[8];
#pragma unroll
    for (int i = 0; i < 8; ++i) acc[i] = f32x4{0.f, 0.f, 0.f, 0.f};

#pragma unroll
    for (int kh = 0; kh < K / 128; ++kh) {
        if (kh) __syncthreads();
#pragma unroll
        for (int i = 0; i < 8; ++i) {
            int idx = t + i * 256;
            int r = idx >> 5, c4 = idx & 31;
            float4 v = *(const float4*)(X + (size_t)(m0 + r) * K + kh * 128 + c4 * 4);
            *(bf16x4*)&ldsX[r][c4 * 4] = cvt4(v);
        }
#pragma unroll
        for (int i = 0; i < 16; ++i) {
            int idx = t + i * 256;
            int r = idx >> 5, c4 = idx & 31;
            float4 v = *(const float4*)(W + (size_t)r * K + kh * 128 + c4 * 4);
            *(bf16x4*)&ldsW[r][c4 * 4] = cvt4(v);
        }
        __syncthreads();

        bf16x8 aA[4];
#pragma unroll
        for (int kc = 0; kc < 4; ++kc)
            aA[kc] = *(const bf16x8*)((const char*)&ldsX[w * 16 + lrow][0] + kc * 64 + lq * 16);
#pragma unroll
        for (int nt = 0; nt < 8; ++nt) {
#pragma unroll
            for (int kc = 0; kc < 4; ++kc) {
                bf16x8 bB = *(const bf16x8*)((const char*)&ldsW[nt * 16 + lrow][0] + kc * 64 + lq * 16);
                acc[nt] = MFMA16(aA[kc], bB, acc[nt]);
            }
        }
    }

#pragma unroll
    for (int nt = 0; nt < 8; ++nt) {
        if (TRANS) {
            // packed r3 store: 4 consecutive s-values (j=0..3) = one bf16x4
            int gm = m0 + w * 16 + lq * 4;       // j = 0 global row
            int b = gm >> 11, s = gm & 2047;
            int col = nt * 16 + lrow;            // o
            int kt = s >> 5, s32 = s & 31;
            int slot = (s32 >> 3) ^ ((col >> 1) & 3);
            bf16x4 y;
#pragma unroll
            for (int j = 0; j < 4; ++j) y[j] = (__bf16)(acc[nt][j] * outScale);
            *(bf16x4*)(out + (((size_t)b * 64 + kt) * 128 + col) * 32 + slot * 8 + (s32 & 7)) = y;
        } else {
#pragma unroll
            for (int j = 0; j < 4; ++j) {
                int gm = m0 + w * 16 + lq * 4 + j;
                int col = nt * 16 + lrow;
                out[(size_t)gm * 128 + col] = (__bf16)(acc[nt][j] * outScale);
            }
        }
    }
}

// ---------------------------------------------------------------------------
// value [8][2048][256] fp32 -> vt PACKED [b][kt=64][v=256][k=32] bf16,
// chunk-XOR baked: slot = ((k>>3) ^ ((v>>1)&3)). Each 32-k tile of all 256
// v-rows is one contiguous 16 KB block.
// ---------------------------------------------------------------------------
__global__ __launch_bounds__(256) void k_vt(const float* __restrict__ V, __bf16* __restrict__ vt) {
    __shared__ __bf16 tile[64][72];
    const int t = threadIdx.x;
    const int b = blockIdx.z, s0 = blockIdx.x * 64, v0 = blockIdx.y * 64;
#pragma unroll
    for (int i = 0; i < 4; ++i) {
        int idx = t + i * 256;
        int r = idx >> 4, c4 = idx & 15;
        float4 x = *(const float4*)(V + ((size_t)b * SEQ + s0 + r) * DV + v0 + c4 * 4);
        *(bf16x4*)&tile[r][c4 * 4] = cvt4(x);
    }
    __syncthreads();
#pragma unroll
    for (int i = 0; i < 4; ++i) {
        int idx = t + i * 256;
        int vv = idx >> 4, c4 = idx & 15;
        bf16x4 y;
        y[0] = tile[c4 * 4 + 0][vv]; y[1] = tile[c4 * 4 + 1][vv];
        y[2] = tile[c4 * 4 + 2][vv]; y[3] = tile[c4 * 4 + 3][vv];
        int v = v0 + vv;
        int kt = (s0 >> 5) + (c4 >> 3);
        int slot = ((c4 >> 1) & 3) ^ ((v >> 1) & 3);
        *(bf16x4*)(vt + (((size_t)b * 64 + kt) * 256 + v) * 32 + slot * 8 + (c4 & 1) * 4) = y;
    }
}

__global__ __launch_bounds__(256) void k_cvt_bf16(const float* __restrict__ src,
                                                  __bf16* __restrict__ dst, int n4) {
    int i = blockIdx.x * 256 + threadIdx.x;
    if (i < n4) {
        float4 v = *(const float4*)(src + (size_t)i * 4);
        *(bf16x4*)(dst + (size_t)i * 4) = cvt4(v);
    }
}

// ---------------------------------------------------------------------------
// Flash attention (unchanged from round 3 — passing)
// ---------------------------------------------------------------------------
__global__ __launch_bounds__(256) void k_flash(const __bf16* __restrict__ r1s,
                                               const __bf16* __restrict__ r2,
                                               const __bf16* __restrict__ r3p,
                                               __bf16* __restrict__ v1) {
    __shared__ __align__(16) __bf16 r2s[4][32 * 128];   // [kcol][d] rows 256B, s(r)=r&15
    __shared__ __align__(16) __bf16 r3s[4][128 * 32];   // [o][k]   rows  64B, s(r)=(r>>1)&3
    __shared__ __bf16 plds[4][16][48];                  // P C->A round-trip (wave-local)

    const int t = threadIdx.x;
    const int bx = (int)((blockIdx.x & 7) * 32 + (blockIdx.x >> 3));  // XCD <-> batch
    const int b = bx >> 5, q0 = (bx & 31) * 64;
    const int w = t >> 6, l = t & 63, lrow = l & 15, lq = l >> 4;

    const __bf16* r1b = r1s + (size_t)b * SEQ * 128;
    const __bf16* r2b = r2 + (size_t)b * SEQ * 128;
    const __bf16* r3b = r3p + (size_t)b * 64 * 128 * 32;   // packed [kt][o][k32]

    bf16x8 aQ[4];
    {
        const __bf16* p = r1b + (size_t)(q0 + w * 16 + lrow) * 128 + lq * 8;
#pragma unroll
        for (int kc = 0; kc < 4; ++kc) aQ[kc] = *(const bf16x8*)(p + kc * 32);
    }

    // per-lane DMA source pointers
    const __bf16* p_r2[2];
    const __bf16* p_r3[2];
#pragma unroll
    for (int q1 = 0; q1 < 2; ++q1) {
        int r = 8 * w + 4 * q1 + (l >> 4);           // r2 tile row (kcol), 4 rows/issue
        int c = (l & 15) ^ (r & 15);
        p_r2[q1] = r2b + (size_t)r * 128 + c * 8;
        p_r3[q1] = r3b + (size_t)(2 * w + q1) * 512 + l * 8;   // packed, contiguous
    }

    auto stage = [&](int bi) {
#pragma unroll
        for (int q1 = 0; q1 < 2; ++q1) {
            gl_lds16(p_r2[q1], &r2s[bi][(2 * w + q1) * 512]);
            gl_lds16(p_r3[q1], &r3s[bi][(2 * w + q1) * 512]);
            p_r2[q1] += 32 * 128;   // next k-tile: 32 kcol rows
            p_r3[q1] += 128 * 32;   // next packed k-tile block
        }
    };

    f32x4 acc[8];
#pragma unroll
    for (int i = 0; i < 8; ++i) acc[i] = f32x4{0.f, 0.f, 0.f, 0.f};
    float mrow[4] = {-INFINITY, -INFINITY, -INFINITY, -INFINITY};
    float lsum[4] = {0.f, 0.f, 0.f, 0.f};

    stage(0); stage(1); stage(2);          // 12 DMA instrs in flight
    for (int it = 0; it < 64; ++it) {
        if (it < 62) { WAITV(8); } else if (it == 62) { WAITV(4); } else { WAITV(0); }
        __builtin_amdgcn_s_barrier();
        __builtin_amdgcn_sched_barrier(0);
        if (it + 3 < 64) stage((it + 3) & 3);
        __builtin_amdgcn_sched_barrier(0);
        const __bf16* R2 = &r2s[it & 3][0];
        const __bf16* R3 = &r3s[it & 3][0];

        // S = r1 . r2^T  (16q x 32k per wave)
        f32x4 sc[2];
#pragma unroll
        for (int ct = 0; ct < 2; ++ct) {
            f32x4 s = f32x4{0.f, 0.f, 0.f, 0.f};
#pragma unroll
            for (int kc = 0; kc < 4; ++kc) {
                int p = (kc * 4 + lq) ^ lrow;
                bf16x8 bb = *(const bf16x8*)&R2[(ct * 16 + lrow) * 128 + p * 8];
                s = MFMA16(aQ[kc], bb, s);
            }
            sc[ct] = s;
        }

        // online softmax
        float pm[4], ps[4], al[4];
#pragma unroll
        for (int j = 0; j < 4; ++j) pm[j] = fmaxf(sc[0][j], sc[1][j]);
#pragma unroll
        for (int off = 1; off <= 8; off <<= 1)
#pragma unroll
            for (int j = 0; j < 4; ++j) pm[j] = fmaxf(pm[j], __shfl_xor(pm[j], off, 64));
#pragma unroll
        for (int j = 0; j < 4; ++j) {
            float mn = fmaxf(mrow[j], pm[j]);
            al[j] = __expf(mrow[j] - mn);
            mrow[j] = mn;
            ps[j] = 0.f;
        }
        float pr[2][4];
#pragma unroll
        for (int ct = 0; ct < 2; ++ct)
#pragma unroll
            for (int j = 0; j < 4; ++j) {
                float p = __expf(sc[ct][j] - mrow[j]);
                pr[ct][j] = p;
                ps[j] += p;
            }
#pragma unroll
        for (int off = 1; off <= 8; off <<= 1)
#pragma unroll
            for (int j = 0; j < 4; ++j) ps[j] += __shfl_xor(ps[j], off, 64);
#pragma unroll
        for (int j = 0; j < 4; ++j) lsum[j] = lsum[j] * al[j] + ps[j];
#pragma unroll
        for (int ot = 0; ot < 8; ++ot)
#pragma unroll
            for (int j = 0; j < 4; ++j) acc[ot][j] *= al[j];

        // P: C-layout -> LDS -> A-layout (wave-local)
#pragma unroll
        for (int ct = 0; ct < 2; ++ct)
#pragma unroll
            for (int j = 0; j < 4; ++j)
                plds[w][lq * 4 + j][ct * 16 + lrow] = (__bf16)pr[ct][j];
        __builtin_amdgcn_s_waitcnt(0xc07f);  // lgkmcnt(0) only — DMA stays in flight
        bf16x8 pA = *(const bf16x8*)&plds[w][lrow][lq * 8];

#pragma unroll
        for (int ot = 0; ot < 8; ++ot) {
            int p = lq ^ ((lrow >> 1) & 3);
            bf16x8 bb = *(const bf16x8*)&R3[(ot * 16 + lrow) * 32 + p * 8];
            acc[ot] = MFMA16(pA, bb, acc[ot]);
        }
    }

#pragma unroll
    for (int ot = 0; ot < 8; ++ot)
#pragma unroll
        for (int j = 0; j < 4; ++j) {
            int q = q0 + w * 16 + lq * 4 + j;
            float v = acc[ot][j] / lsum[j];
            v1[((size_t)b * SEQ + q) * 128 + ot * 16 + lrow] = (__bf16)v;
        }
}

// ---------------------------------------------------------------------------
// out = mask@value + (P@r3)@Wout^T.  v6: STREAM-SPLIT wave roles.
// Per-wave vmcnt FIFO is in-order -> mixing HBM (mask) and L2 (vt) DMAs in
// one wave retires everything at HBM cadence (the measured 105 cyc/instr).
// Fix: waves 0-3 DMA only vt (packed, 16 KB contiguous, 3-buf, counted
// vmcnt 4); waves 4-7 DMA only mask (BK_m=64 epochs = 256 B runs, 3-epoch
// buffer, counted vmcnt). 512-thr wg, grid 512 -> 2 wg/CU = 16 waves/CU.
// All 8 waves compute 16q x 64v (acc = 16 VGPR -> no spill). LDS 72 KB.
// ---------------------------------------------------------------------------
__global__ __launch_bounds__(512, 4) void k_out(const float* __restrict__ mask,
                                                const __bf16* __restrict__ vtp,
                                                const __bf16* __restrict__ v1,
                                                const __bf16* __restrict__ wob,
                                                float* __restrict__ out) {
    __shared__ __align__(16) __bf16 vbuf[3][256 * 32];  // 48 KB, slot-XOR baked
    __shared__ __align__(16) float mbuf[3][32 * 64];    // 24 KB, chunk-XOR baked

    const int t = threadIdx.x;
    const int bid = (int)((blockIdx.x & 7) * 64 + (blockIdx.x >> 3));  // XCD = batch
    const int m0 = bid * 32;
    const int b = m0 >> 11, q0 = m0 & 2047;
    const int w = t >> 6, l = t & 63, lrow = l & 15, lq = l >> 4;
    const int rg = w & 1, cg = w >> 1;   // 2 row-groups x 4 col-groups (64 v each)

    f32x4 acc[4];
#pragma unroll
    for (int i = 0; i < 4; ++i) acc[i] = f32x4{0.f, 0.f, 0.f, 0.f};

    // ---- staging pointers (role-split) ----
    const __bf16* vsrc[4];   // vt waves (w<4): 4 instrs/tile, 1 KB each, contiguous
    const float* msrc[2];    // mask waves (w>=4): 1 instr/iter; rows 4/instr, 256 B runs
    if (w < 4) {
#pragma unroll
        for (int i = 0; i < 4; ++i)
            vsrc[i] = vtp + (size_t)b * 64 * 8192 + (w * 4 + i) * 512 + l * 8;
    } else {
        const int m = w - 4;
#pragma unroll
        for (int s = 0; s < 2; ++s) {
            int r = 4 * (m * 2 + s) + (l >> 4);
            int c = (l & 15) ^ (r & 7);
            msrc[s] = mask + ((size_t)(b * 2048 + q0 + r)) * 2048 + c * 4;
        }
    }

    // ---- prologue ----
    if (w < 4) {
#pragma unroll
        for (int kt = 0; kt < 2; ++kt)
#pragma unroll
            for (int i = 0; i < 4; ++i)
                gl_lds16(vsrc[i] + (size_t)kt * 8192, &vbuf[kt][(w * 4 + i) * 512]);
    } else {
        const int m = w - 4;
#pragma unroll
        for (int s = 0; s < 2; ++s)
            gl_lds16(msrc[s], &mbuf[0][(m * 2 + s) * 256]);
    }

    for (int it = 0; it < 64; ++it) {
        // mask waves: issue next-epoch instr (pre-barrier safe: 3-epoch buffer,
        // readers of target buffer finished >=3 barriers ago), then counted wait.
        if (w >= 4) {
            const int m = w - 4;
            if (it <= 61) {
                int e = (it >> 1) + 1, s = it & 1;
                gl_lds16(msrc[s] + (size_t)e * 64, &mbuf[e % 3][(m * 2 + s) * 256]);
            }
            if ((it & 1) == 0) {
                if (it <= 60) { WAITV(1); } else { WAITV(0); }
            }
        } else {
            if (it < 63) { WAITV(4); } else { WAITV(0); }
        }
        __builtin_amdgcn_s_barrier();
        __builtin_amdgcn_sched_barrier(0);
        // vt waves: issue stage(it+2) post-barrier (3-buf: readers were iter it-1)
        if (w < 4 && it + 2 < 64) {
            int kt = it + 2;
#pragma unroll
            for (int i = 0; i < 4; ++i)
                gl_lds16(vsrc[i] + (size_t)kt * 8192, &vbuf[kt % 3][(w * 4 + i) * 512]);
        }
        __builtin_amdgcn_sched_barrier(0);

        // ---- compute (all 8 waves): 16q x 64v, BK=32 ----
        const float* Mb = &mbuf[(it >> 1) % 3][0];
        const __bf16* V = &vbuf[it % 3][0];
        const int h = it & 1;
        int c0 = (h * 8 + lq * 2) ^ (lrow & 7);
        int c1 = (h * 8 + lq * 2 + 1) ^ (lrow & 7);
        float4 f0 = *(const float4*)&Mb[(rg * 16 + lrow) * 64 + c0 * 4];
        float4 f1 = *(const float4*)&Mb[(rg * 16 + lrow) * 64 + c1 * 4];
        bf16x8 aM;
        aM[0] = (__bf16)f0.x; aM[1] = (__bf16)f0.y; aM[2] = (__bf16)f0.z; aM[3] = (__bf16)f0.w;
        aM[4] = (__bf16)f1.x; aM[5] = (__bf16)f1.y; aM[6] = (__bf16)f1.z; aM[7] = (__bf16)f1.w;

        const int pv = lq ^ ((lrow >> 1) & 3);
#pragma unroll
        for (int vt8 = 0; vt8 < 4; ++vt8) {
            bf16x8 bb = *(const bf16x8*)&V[(cg * 64 + vt8 * 16 + lrow) * 32 + pv * 8];
            acc[vt8] = MFMA16(aM, bb, acc[vt8]);
        }
    }

    // epilogue: + v1 @ Wout^T (small, direct from global/L2)
    bf16x8 aV[4];
#pragma unroll
    for (int oc = 0; oc < 4; ++oc)
        aV[oc] = *(const bf16x8*)(v1 + (size_t)(m0 + rg * 16 + lrow) * 128 + oc * 32 + lq * 8);
#pragma unroll
    for (int vt8 = 0; vt8 < 4; ++vt8) {
#pragma unroll
        for (int oc = 0; oc < 4; ++oc) {
            bf16x8 bb = *(const bf16x8*)(wob + (size_t)(cg * 64 + vt8 * 16 + lrow) * 128 + oc * 32 + lq * 8);
            acc[vt8] = MFMA16(aV[oc], bb, acc[vt8]);
        }
    }

#pragma unroll
    for (int vt8 = 0; vt8 < 4; ++vt8)
#pragma unroll
        for (int j = 0; j < 4; ++j) {
            int gq = m0 + rg * 16 + lq * 4 + j;
            out[(size_t)gq * 256 + cg * 64 + vt8 * 16 + lrow] = acc[vt8][j];
        }
}

// ---------------------------------------------------------------------------
extern "C" void kernel_launch(void* const* d_in, const int* in_sizes, int n_in,
                              void* d_out, int out_size, void* d_ws, size_t ws_size,
                              hipStream_t stream) {
    const float* q    = (const float*)d_in[0];
    const float* k    = (const float*)d_in[1];
    const float* v    = (const float*)d_in[2];
    const float* mask = (const float*)d_in[3];
    const float* W0   = (const float*)d_in[4];
    const float* W1   = (const float*)d_in[5];
    const float* W2   = (const float*)d_in[6];
    const float* Wout = (const float*)d_in[7];
    float* out = (float*)d_out;

    char* ws = (char*)d_ws;
    __bf16* r1s = (__bf16*)(ws);                  // [8][2048][128] bf16 (pre-scaled 4.5)
    __bf16* r2b = (__bf16*)(ws + (4ull << 20));   // [8][2048][128] bf16
    __bf16* r3t = (__bf16*)(ws + (8ull << 20));   // [8][64][128][32] bf16 PACKED
    __bf16* vtb = (__bf16*)(ws + (12ull << 20));  // [8][64][256][32] bf16 PACKED
    __bf16* wob = (__bf16*)(ws + (20ull << 20));  // [256][128] bf16
    __bf16* v1b = (__bf16*)(ws + (21ull << 20));  // [8][2048][128] bf16

    k_proj<128, 0><<<256, 256, 0, stream>>>(q, W0, r1s, QK_SCALE);
    k_proj<128, 0><<<256, 256, 0, stream>>>(k, W1, r2b, 1.0f);
    k_proj<256, 1><<<256, 256, 0, stream>>>(v, W2, r3t, 1.0f);
    k_vt<<<dim3(32, 4, 8), 256, 0, stream>>>(v, vtb);
    k_cvt_bf16<<<32, 256, 0, stream>>>(Wout, wob, 8192);
    k_flash<<<256, 256, 0, stream>>>(r1s, r2b, r3t, v1b);
    k_out<<<512, 512, 0, stream>>>(mask, vtb, v1b, wob, out);
}

// Round 5
// 349.082 us; speedup vs baseline: 1.5000x; 1.1258x over previous
//
#include <hip/hip_runtime.h>
#include <cstdint>

typedef __attribute__((ext_vector_type(8))) __bf16 bf16x8;
typedef __attribute__((ext_vector_type(4))) __bf16 bf16x4;
typedef __attribute__((ext_vector_type(4))) float f32x4;

#define MFMA16(a, b, c) __builtin_amdgcn_mfma_f32_16x16x32_bf16((a), (b), (c), 0, 0, 0)
// counted waitcnt: NEVER drain vmcnt(0) in the main loop (T4).
#define WAITV(N) asm volatile("s_waitcnt vmcnt(" #N ")" ::: "memory")

static constexpr int SEQ = 2048;
static constexpr int DV = 256;
static constexpr float QK_SCALE = 4.5f;  // qk / INV_SCALE, INV_SCALE = 1/(0.5*9)

__device__ __forceinline__ bf16x4 cvt4(float4 v) {
    bf16x4 y;
    y[0] = (__bf16)v.x; y[1] = (__bf16)v.y; y[2] = (__bf16)v.z; y[3] = (__bf16)v.w;
    return y;
}

// async global->LDS DMA, 16B per lane; LDS dest wave-uniform base + lane*16.
__device__ __forceinline__ void gl_lds16(const void* g, void* l) {
    __builtin_amdgcn_global_load_lds((const __attribute__((address_space(1))) uint32_t*)g,
                                     (__attribute__((address_space(3))) uint32_t*)l, 16, 0, 0);
}

// ---------------------------------------------------------------------------
// Projection GEMM. TRANS=1 writes r3 PACKED: [b][kt=64][o=128][k=32] bf16
// with chunk-XOR baked (slot = (k>>3) ^ ((o>>1)&3)).
// ---------------------------------------------------------------------------
template <int K, int TRANS>
__global__ __launch_bounds__(256) void k_proj(const float* __restrict__ X,
                                              const float* __restrict__ W,
                                              __bf16* __restrict__ out,
                                              float outScale) {
    __shared__ __bf16 ldsX[64][136];
    __shared__ __bf16 ldsW[128][136];

    const int t = threadIdx.x;
    const int m0 = blockIdx.x * 64;
    const int w = t >> 6, l = t & 63, lrow = l & 15, lq = l >> 4;

    f32x4 acc[8];
#pragma unroll
    for (int i = 0; i < 8; ++i) acc[i] = f32x4{0.f, 0.f, 0.f, 0.f};

#pragma unroll
    for (int kh = 0; kh < K / 128; ++kh) {
        if (kh) __syncthreads();
#pragma unroll
        for (int i = 0; i < 8; ++i) {
            int idx = t + i * 256;
            int r = idx >> 5, c4 = idx & 31;
            float4 v = *(const float4*)(X + (size_t)(m0 + r) * K + kh * 128 + c4 * 4);
            *(bf16x4*)&ldsX[r][c4 * 4] = cvt4(v);
        }
#pragma unroll
        for (int i = 0; i < 16; ++i) {
            int idx = t + i * 256;
            int r = idx >> 5, c4 = idx & 31;
            float4 v = *(const float4*)(W + (size_t)r * K + kh * 128 + c4 * 4);
            *(bf16x4*)&ldsW[r][c4 * 4] = cvt4(v);
        }
        __syncthreads();

        bf16x8 aA[4];
#pragma unroll
        for (int kc = 0; kc < 4; ++kc)
            aA[kc] = *(const bf16x8*)((const char*)&ldsX[w * 16 + lrow][0] + kc * 64 + lq * 16);
#pragma unroll
        for (int nt = 0; nt < 8; ++nt) {
#pragma unroll
            for (int kc = 0; kc < 4; ++kc) {
                bf16x8 bB = *(const bf16x8*)((const char*)&ldsW[nt * 16 + lrow][0] + kc * 64 + lq * 16);
                acc[nt] = MFMA16(aA[kc], bB, acc[nt]);
            }
        }
    }

#pragma unroll
    for (int nt = 0; nt < 8; ++nt) {
        if (TRANS) {
            // packed r3 store: 4 consecutive s-values (j=0..3) = one bf16x4
            int gm = m0 + w * 16 + lq * 4;       // j = 0 global row
            int b = gm >> 11, s = gm & 2047;
            int col = nt * 16 + lrow;            // o
            int kt = s >> 5, s32 = s & 31;
            int slot = (s32 >> 3) ^ ((col >> 1) & 3);
            bf16x4 y;
#pragma unroll
            for (int j = 0; j < 4; ++j) y[j] = (__bf16)(acc[nt][j] * outScale);
            *(bf16x4*)(out + (((size_t)b * 64 + kt) * 128 + col) * 32 + slot * 8 + (s32 & 7)) = y;
        } else {
#pragma unroll
            for (int j = 0; j < 4; ++j) {
                int gm = m0 + w * 16 + lq * 4 + j;
                int col = nt * 16 + lrow;
                out[(size_t)gm * 128 + col] = (__bf16)(acc[nt][j] * outScale);
            }
        }
    }
}

// ---------------------------------------------------------------------------
// value [8][2048][256] fp32 -> vt PACKED [b][kt=64][v=256][k=32] bf16,
// chunk-XOR baked: slot = ((k>>3) ^ ((v>>1)&3)).
// ---------------------------------------------------------------------------
__global__ __launch_bounds__(256) void k_vt(const float* __restrict__ V, __bf16* __restrict__ vt) {
    __shared__ __bf16 tile[64][72];
    const int t = threadIdx.x;
    const int b = blockIdx.z, s0 = blockIdx.x * 64, v0 = blockIdx.y * 64;
#pragma unroll
    for (int i = 0; i < 4; ++i) {
        int idx = t + i * 256;
        int r = idx >> 4, c4 = idx & 15;
        float4 x = *(const float4*)(V + ((size_t)b * SEQ + s0 + r) * DV + v0 + c4 * 4);
        *(bf16x4*)&tile[r][c4 * 4] = cvt4(x);
    }
    __syncthreads();
#pragma unroll
    for (int i = 0; i < 4; ++i) {
        int idx = t + i * 256;
        int vv = idx >> 4, c4 = idx & 15;
        bf16x4 y;
        y[0] = tile[c4 * 4 + 0][vv]; y[1] = tile[c4 * 4 + 1][vv];
        y[2] = tile[c4 * 4 + 2][vv]; y[3] = tile[c4 * 4 + 3][vv];
        int v = v0 + vv;
        int kt = (s0 >> 5) + (c4 >> 3);
        int slot = ((c4 >> 1) & 3) ^ ((v >> 1) & 3);
        *(bf16x4*)(vt + (((size_t)b * 64 + kt) * 256 + v) * 32 + slot * 8 + (c4 & 1) * 4) = y;
    }
}

__global__ __launch_bounds__(256) void k_cvt_bf16(const float* __restrict__ src,
                                                  __bf16* __restrict__ dst, int n4) {
    int i = blockIdx.x * 256 + threadIdx.x;
    if (i < n4) {
        float4 v = *(const float4*)(src + (size_t)i * 4);
        *(bf16x4*)(dst + (size_t)i * 4) = cvt4(v);
    }
}

// ---------------------------------------------------------------------------
// Flash attention v7: SPLIT-K x2 + deferred cross-lane sum.
// grid 512 (XCD-swizzled; each XCD = one batch) -> 2 wg/CU = 2 waves/SIMD:
// the two independent wgs hide each other's serial-latency stalls (bpermute
// chains, exp, P LDS round-trip) that a single wave/SIMD fully exposes.
// Each wg does 32 of 64 k-tiles (identical per-iter code); partial
// (O_norm, m, l) written to ws, merged exactly by k_comb.
// In-loop, only the MAX needs cross-lane reduction (4 bpermutes); the sum
// is kept per-lane (al uniform per 16-lane k-group -> linearity holds) and
// reduced once in the epilogue.
// ---------------------------------------------------------------------------
__global__ __launch_bounds__(256) void k_flash(const __bf16* __restrict__ r1s,
                                               const __bf16* __restrict__ r2,
                                               const __bf16* __restrict__ r3p,
                                               __bf16* __restrict__ v1p,
                                               float* __restrict__ ml) {
    __shared__ __align__(16) __bf16 r2s[4][32 * 128];   // [kcol][d] rows 256B, s(r)=r&15
    __shared__ __align__(16) __bf16 r3s[4][128 * 32];   // [o][k]   rows  64B, s(r)=(r>>1)&3
    __shared__ __bf16 plds[4][16][48];                  // P C->A round-trip (wave-local)

    const int t = threadIdx.x;
    // 512 wgs: 64 per XCD = one batch per XCD (both k-halves share the L2 panel)
    const int bx = (int)((blockIdx.x & 7) * 64 + (blockIdx.x >> 3));
    const int b = bx >> 6, rem = bx & 63, q0 = (rem >> 1) * 64, kh = rem & 1;
    const int w = t >> 6, l = t & 63, lrow = l & 15, lq = l >> 4;

    const __bf16* r1b = r1s + (size_t)b * SEQ * 128;
    const __bf16* r2b = r2 + (size_t)b * SEQ * 128 + (size_t)kh * 1024 * 128;
    const __bf16* r3b = r3p + (size_t)b * 64 * 128 * 32 + (size_t)kh * 32 * 128 * 32;

    bf16x8 aQ[4];
    {
        const __bf16* p = r1b + (size_t)(q0 + w * 16 + lrow) * 128 + lq * 8;
#pragma unroll
        for (int kc = 0; kc < 4; ++kc) aQ[kc] = *(const bf16x8*)(p + kc * 32);
    }

    // per-lane DMA source pointers
    const __bf16* p_r2[2];
    const __bf16* p_r3[2];
#pragma unroll
    for (int q1 = 0; q1 < 2; ++q1) {
        int r = 8 * w + 4 * q1 + (l >> 4);           // r2 tile row (kcol), 4 rows/issue
        int c = (l & 15) ^ (r & 15);
        p_r2[q1] = r2b + (size_t)r * 128 + c * 8;
        p_r3[q1] = r3b + (size_t)(2 * w + q1) * 512 + l * 8;   // packed, contiguous
    }

    auto stage = [&](int bi) {
#pragma unroll
        for (int q1 = 0; q1 < 2; ++q1) {
            gl_lds16(p_r2[q1], &r2s[bi][(2 * w + q1) * 512]);
            gl_lds16(p_r3[q1], &r3s[bi][(2 * w + q1) * 512]);
            p_r2[q1] += 32 * 128;   // next k-tile: 32 kcol rows
            p_r3[q1] += 128 * 32;   // next packed k-tile block
        }
    };

    f32x4 acc[8];
#pragma unroll
    for (int i = 0; i < 8; ++i) acc[i] = f32x4{0.f, 0.f, 0.f, 0.f};
    float mrow[4] = {-INFINITY, -INFINITY, -INFINITY, -INFINITY};
    float lsum[4] = {0.f, 0.f, 0.f, 0.f};   // PER-LANE partial (deferred reduction)

    stage(0); stage(1); stage(2);          // 12 DMA instrs in flight
    for (int it = 0; it < 32; ++it) {
        if (it < 30) { WAITV(8); } else if (it == 30) { WAITV(4); } else { WAITV(0); }
        __builtin_amdgcn_s_barrier();
        __builtin_amdgcn_sched_barrier(0);
        if (it + 3 < 32) stage((it + 3) & 3);
        __builtin_amdgcn_sched_barrier(0);
        const __bf16* R2 = &r2s[it & 3][0];
        const __bf16* R3 = &r3s[it & 3][0];

        // S = r1 . r2^T  (16q x 32k per wave)
        f32x4 sc[2];
#pragma unroll
        for (int ct = 0; ct < 2; ++ct) {
            f32x4 s = f32x4{0.f, 0.f, 0.f, 0.f};
#pragma unroll
            for (int kc = 0; kc < 4; ++kc) {
                int p = (kc * 4 + lq) ^ lrow;
                bf16x8 bb = *(const bf16x8*)&R2[(ct * 16 + lrow) * 128 + p * 8];
                s = MFMA16(aQ[kc], bb, s);
            }
            sc[ct] = s;
        }

        // online softmax: only the MAX is cross-lane in-loop
        float pm[4], al[4];
#pragma unroll
        for (int j = 0; j < 4; ++j) pm[j] = fmaxf(sc[0][j], sc[1][j]);
#pragma unroll
        for (int off = 1; off <= 8; off <<= 1)
#pragma unroll
            for (int j = 0; j < 4; ++j) pm[j] = fmaxf(pm[j], __shfl_xor(pm[j], off, 64));
#pragma unroll
        for (int j = 0; j < 4; ++j) {
            float mn = fmaxf(mrow[j], pm[j]);
            al[j] = __expf(mrow[j] - mn);
            mrow[j] = mn;
        }
        float pr[2][4];
#pragma unroll
        for (int ct = 0; ct < 2; ++ct)
#pragma unroll
            for (int j = 0; j < 4; ++j)
                pr[ct][j] = __expf(sc[ct][j] - mrow[j]);
#pragma unroll
        for (int j = 0; j < 4; ++j)
            lsum[j] = lsum[j] * al[j] + pr[0][j] + pr[1][j];   // per-lane only
#pragma unroll
        for (int ot = 0; ot < 8; ++ot)
#pragma unroll
            for (int j = 0; j < 4; ++j) acc[ot][j] *= al[j];

        // P: C-layout -> LDS -> A-layout (wave-local)
#pragma unroll
        for (int ct = 0; ct < 2; ++ct)
#pragma unroll
            for (int j = 0; j < 4; ++j)
                plds[w][lq * 4 + j][ct * 16 + lrow] = (__bf16)pr[ct][j];
        __builtin_amdgcn_s_waitcnt(0xc07f);  // lgkmcnt(0) only — DMA stays in flight
        bf16x8 pA = *(const bf16x8*)&plds[w][lrow][lq * 8];

#pragma unroll
        for (int ot = 0; ot < 8; ++ot) {
            int p = lq ^ ((lrow >> 1) & 3);
            bf16x8 bb = *(const bf16x8*)&R3[(ot * 16 + lrow) * 32 + p * 8];
            acc[ot] = MFMA16(pA, bb, acc[ot]);
        }
    }

    // epilogue: one cross-lane sum reduction (deferred from loop)
#pragma unroll
    for (int off = 1; off <= 8; off <<= 1)
#pragma unroll
        for (int j = 0; j < 4; ++j) lsum[j] += __shfl_xor(lsum[j], off, 64);

    __bf16* vp = v1p + (size_t)kh * 8 * SEQ * 128;
#pragma unroll
    for (int ot = 0; ot < 8; ++ot)
#pragma unroll
        for (int j = 0; j < 4; ++j) {
            int q = q0 + w * 16 + lq * 4 + j;
            float v = acc[ot][j] / lsum[j];
            vp[((size_t)b * SEQ + q) * 128 + ot * 16 + lrow] = (__bf16)v;
        }
    if (lrow == 0) {
#pragma unroll
        for (int j = 0; j < 4; ++j) {
            size_t row = (size_t)b * SEQ + q0 + w * 16 + lq * 4 + j;
            ml[((size_t)kh * 8 * SEQ + row) * 2 + 0] = mrow[j];
            ml[((size_t)kh * 8 * SEQ + row) * 2 + 1] = lsum[j];
        }
    }
}

// ---------------------------------------------------------------------------
// Merge the two split-K partials (exact): v = (v0*w0 + v1*w1)/(w0+w1),
// w_i = l_i * exp(m_i - max(m0,m1)).  16 threads/row, 8 cols each.
// ---------------------------------------------------------------------------
__global__ __launch_bounds__(256) void k_comb(const __bf16* __restrict__ v1p,
                                              const float* __restrict__ ml,
                                              __bf16* __restrict__ v1) {
    const int NROW = 8 * SEQ;
    int idx = blockIdx.x * 256 + threadIdx.x;
    int row = idx >> 4, c8 = (idx & 15) * 8;
    float m0 = ml[(size_t)row * 2 + 0], l0 = ml[(size_t)row * 2 + 1];
    float m1 = ml[((size_t)NROW + row) * 2 + 0], l1 = ml[((size_t)NROW + row) * 2 + 1];
    float M = fmaxf(m0, m1);
    float w0 = l0 * __expf(m0 - M), w1 = l1 * __expf(m1 - M);
    float inv = 1.f / (w0 + w1);
    w0 *= inv; w1 *= inv;
    bf16x8 a = *(const bf16x8*)(v1p + (size_t)row * 128 + c8);
    bf16x8 bb = *(const bf16x8*)(v1p + ((size_t)NROW + row) * 128 + c8);
    bf16x8 o;
#pragma unroll
    for (int j = 0; j < 8; ++j) o[j] = (__bf16)((float)a[j] * w0 + (float)bb[j] * w1);
    *(bf16x8*)(v1 + (size_t)row * 128 + c8) = o;
}

// ---------------------------------------------------------------------------
// out = mask@value + (P@r3)@Wout^T.  (unchanged from round 4 — stream-split)
// ---------------------------------------------------------------------------
__global__ __launch_bounds__(512, 4) void k_out(const float* __restrict__ mask,
                                                const __bf16* __restrict__ vtp,
                                                const __bf16* __restrict__ v1,
                                                const __bf16* __restrict__ wob,
                                                float* __restrict__ out) {
    __shared__ __align__(16) __bf16 vbuf[3][256 * 32];  // 48 KB, slot-XOR baked
    __shared__ __align__(16) float mbuf[3][32 * 64];    // 24 KB, chunk-XOR baked

    const int t = threadIdx.x;
    const int bid = (int)((blockIdx.x & 7) * 64 + (blockIdx.x >> 3));  // XCD = batch
    const int m0 = bid * 32;
    const int b = m0 >> 11, q0 = m0 & 2047;
    const int w = t >> 6, l = t & 63, lrow = l & 15, lq = l >> 4;
    const int rg = w & 1, cg = w >> 1;   // 2 row-groups x 4 col-groups (64 v each)

    f32x4 acc[4];
#pragma unroll
    for (int i = 0; i < 4; ++i) acc[i] = f32x4{0.f, 0.f, 0.f, 0.f};

    // ---- staging pointers (role-split) ----
    const __bf16* vsrc[4];   // vt waves (w<4): 4 instrs/tile, 1 KB each, contiguous
    const float* msrc[2];    // mask waves (w>=4): 1 instr/iter; rows 4/instr, 256 B runs
    if (w < 4) {
#pragma unroll
        for (int i = 0; i < 4; ++i)
            vsrc[i] = vtp + (size_t)b * 64 * 8192 + (w * 4 + i) * 512 + l * 8;
    } else {
        const int m = w - 4;
#pragma unroll
        for (int s = 0; s < 2; ++s) {
            int r = 4 * (m * 2 + s) + (l >> 4);
            int c = (l & 15) ^ (r & 7);
            msrc[s] = mask + ((size_t)(b * 2048 + q0 + r)) * 2048 + c * 4;
        }
    }

    // ---- prologue ----
    if (w < 4) {
#pragma unroll
        for (int kt = 0; kt < 2; ++kt)
#pragma unroll
            for (int i = 0; i < 4; ++i)
                gl_lds16(vsrc[i] + (size_t)kt * 8192, &vbuf[kt][(w * 4 + i) * 512]);
    } else {
        const int m = w - 4;
#pragma unroll
        for (int s = 0; s < 2; ++s)
            gl_lds16(msrc[s], &mbuf[0][(m * 2 + s) * 256]);
    }

    for (int it = 0; it < 64; ++it) {
        if (w >= 4) {
            const int m = w - 4;
            if (it <= 61) {
                int e = (it >> 1) + 1, s = it & 1;
                gl_lds16(msrc[s] + (size_t)e * 64, &mbuf[e % 3][(m * 2 + s) * 256]);
            }
            if ((it & 1) == 0) {
                if (it <= 60) { WAITV(1); } else { WAITV(0); }
            }
        } else {
            if (it < 63) { WAITV(4); } else { WAITV(0); }
        }
        __builtin_amdgcn_s_barrier();
        __builtin_amdgcn_sched_barrier(0);
        if (w < 4 && it + 2 < 64) {
            int kt = it + 2;
#pragma unroll
            for (int i = 0; i < 4; ++i)
                gl_lds16(vsrc[i] + (size_t)kt * 8192, &vbuf[kt % 3][(w * 4 + i) * 512]);
        }
        __builtin_amdgcn_sched_barrier(0);

        // ---- compute (all 8 waves): 16q x 64v, BK=32 ----
        const float* Mb = &mbuf[(it >> 1) % 3][0];
        const __bf16* V = &vbuf[it % 3][0];
        const int h = it & 1;
        int c0 = (h * 8 + lq * 2) ^ (lrow & 7);
        int c1 = (h * 8 + lq * 2 + 1) ^ (lrow & 7);
        float4 f0 = *(const float4*)&Mb[(rg * 16 + lrow) * 64 + c0 * 4];
        float4 f1 = *(const float4*)&Mb[(rg * 16 + lrow) * 64 + c1 * 4];
        bf16x8 aM;
        aM[0] = (__bf16)f0.x; aM[1] = (__bf16)f0.y; aM[2] = (__bf16)f0.z; aM[3] = (__bf16)f0.w;
        aM[4] = (__bf16)f1.x; aM[5] = (__bf16)f1.y; aM[6] = (__bf16)f1.z; aM[7] = (__bf16)f1.w;

        const int pv = lq ^ ((lrow >> 1) & 3);
#pragma unroll
        for (int vt8 = 0; vt8 < 4; ++vt8) {
            bf16x8 bb = *(const bf16x8*)&V[(cg * 64 + vt8 * 16 + lrow) * 32 + pv * 8];
            acc[vt8] = MFMA16(aM, bb, acc[vt8]);
        }
    }

    // epilogue: + v1 @ Wout^T (small, direct from global/L2)
    bf16x8 aV[4];
#pragma unroll
    for (int oc = 0; oc < 4; ++oc)
        aV[oc] = *(const bf16x8*)(v1 + (size_t)(m0 + rg * 16 + lrow) * 128 + oc * 32 + lq * 8);
#pragma unroll
    for (int vt8 = 0; vt8 < 4; ++vt8) {
#pragma unroll
        for (int oc = 0; oc < 4; ++oc) {
            bf16x8 bb = *(const bf16x8*)(wob + (size_t)(cg * 64 + vt8 * 16 + lrow) * 128 + oc * 32 + lq * 8);
            acc[vt8] = MFMA16(aV[oc], bb, acc[vt8]);
        }
    }

#pragma unroll
    for (int vt8 = 0; vt8 < 4; ++vt8)
#pragma unroll
        for (int j = 0; j < 4; ++j) {
            int gq = m0 + rg * 16 + lq * 4 + j;
            out[(size_t)gq * 256 + cg * 64 + vt8 * 16 + lrow] = acc[vt8][j];
        }
}

// ---------------------------------------------------------------------------
extern "C" void kernel_launch(void* const* d_in, const int* in_sizes, int n_in,
                              void* d_out, int out_size, void* d_ws, size_t ws_size,
                              hipStream_t stream) {
    const float* q    = (const float*)d_in[0];
    const float* k    = (const float*)d_in[1];
    const float* v    = (const float*)d_in[2];
    const float* mask = (const float*)d_in[3];
    const float* W0   = (const float*)d_in[4];
    const float* W1   = (const float*)d_in[5];
    const float* W2   = (const float*)d_in[6];
    const float* Wout = (const float*)d_in[7];
    float* out = (float*)d_out;

    char* ws = (char*)d_ws;
    __bf16* r1s = (__bf16*)(ws);                  // [8][2048][128] bf16 (pre-scaled 4.5)
    __bf16* r2b = (__bf16*)(ws + (4ull << 20));   // [8][2048][128] bf16
    __bf16* r3t = (__bf16*)(ws + (8ull << 20));   // [8][64][128][32] bf16 PACKED
    __bf16* vtb = (__bf16*)(ws + (12ull << 20));  // [8][64][256][32] bf16 PACKED
    __bf16* wob = (__bf16*)(ws + (20ull << 20));  // [256][128] bf16
    __bf16* v1b = (__bf16*)(ws + (21ull << 20));  // [8][2048][128] bf16
    __bf16* v1p = (__bf16*)(ws + (25ull << 20));  // [2][8][2048][128] bf16 partials
    float*  mlb = (float*)(ws + (33ull << 20));   // [2][8*2048][2] f32 (m, l)

    k_proj<128, 0><<<256, 256, 0, stream>>>(q, W0, r1s, QK_SCALE);
    k_proj<128, 0><<<256, 256, 0, stream>>>(k, W1, r2b, 1.0f);
    k_proj<256, 1><<<256, 256, 0, stream>>>(v, W2, r3t, 1.0f);
    k_vt<<<dim3(32, 4, 8), 256, 0, stream>>>(v, vtb);
    k_cvt_bf16<<<32, 256, 0, stream>>>(Wout, wob, 8192);
    k_flash<<<512, 256, 0, stream>>>(r1s, r2b, r3t, v1p, mlb);
    k_comb<<<1024, 256, 0, stream>>>(v1p, mlb, v1b);
    k_out<<<512, 512, 0, stream>>>(mask, vtb, v1b, wob, out);
}

// Round 6
// 335.080 us; speedup vs baseline: 1.5627x; 1.0418x over previous
//
#include <hip/hip_runtime.h>
#include <cstdint>

typedef __attribute__((ext_vector_type(8))) __bf16 bf16x8;
typedef __attribute__((ext_vector_type(4))) __bf16 bf16x4;
typedef __attribute__((ext_vector_type(4))) float f32x4;

#define MFMA16(a, b, c) __builtin_amdgcn_mfma_f32_16x16x32_bf16((a), (b), (c), 0, 0, 0)
// counted waitcnt: NEVER drain vmcnt(0) in the main loop (T4).
#define WAITV(N) asm volatile("s_waitcnt vmcnt(" #N ")" ::: "memory")

static constexpr int SEQ = 2048;
static constexpr int DV = 256;
static constexpr float QK_SCALE = 4.5f;  // qk / INV_SCALE, INV_SCALE = 1/(0.5*9)

__device__ __forceinline__ bf16x4 cvt4(float4 v) {
    bf16x4 y;
    y[0] = (__bf16)v.x; y[1] = (__bf16)v.y; y[2] = (__bf16)v.z; y[3] = (__bf16)v.w;
    return y;
}

// async global->LDS DMA, 16B per lane; LDS dest wave-uniform base + lane*16.
__device__ __forceinline__ void gl_lds16(const void* g, void* l) {
    __builtin_amdgcn_global_load_lds((const __attribute__((address_space(1))) uint32_t*)g,
                                     (__attribute__((address_space(3))) uint32_t*)l, 16, 0, 0);
}

// ---------------------------------------------------------------------------
// Projection GEMM body (device fn; shared mem passed in). TRANS=1 writes r3
// PACKED [b][kt=64][o=128][k=32] bf16, chunk-XOR baked (slot=(k>>3)^((o>>1)&3)).
// ---------------------------------------------------------------------------
template <int K, int TRANS>
__device__ __forceinline__ void proj_body(const float* __restrict__ X,
                                          const float* __restrict__ W,
                                          __bf16* __restrict__ out,
                                          float outScale, int m0, char* smem) {
    auto ldsX = (__bf16(*)[136])smem;                       // [64][136]
    auto ldsW = (__bf16(*)[136])(smem + 64 * 136 * 2);      // [128][136]

    const int t = threadIdx.x;
    const int w = t >> 6, l = t & 63, lrow = l & 15, lq = l >> 4;

    f32x4 acc[8];
#pragma unroll
    for (int i = 0; i < 8; ++i) acc[i] = f32x4{0.f, 0.f, 0.f, 0.f};

#pragma unroll
    for (int kh = 0; kh < K / 128; ++kh) {
        if (kh) __syncthreads();
#pragma unroll
        for (int i = 0; i < 8; ++i) {
            int idx = t + i * 256;
            int r = idx >> 5, c4 = idx & 31;
            float4 v = *(const float4*)(X + (size_t)(m0 + r) * K + kh * 128 + c4 * 4);
            *(bf16x4*)&ldsX[r][c4 * 4] = cvt4(v);
        }
#pragma unroll
        for (int i = 0; i < 16; ++i) {
            int idx = t + i * 256;
            int r = idx >> 5, c4 = idx & 31;
            float4 v = *(const float4*)(W + (size_t)r * K + kh * 128 + c4 * 4);
            *(bf16x4*)&ldsW[r][c4 * 4] = cvt4(v);
        }
        __syncthreads();

        bf16x8 aA[4];
#pragma unroll
        for (int kc = 0; kc < 4; ++kc)
            aA[kc] = *(const bf16x8*)((const char*)&ldsX[w * 16 + lrow][0] + kc * 64 + lq * 16);
#pragma unroll
        for (int nt = 0; nt < 8; ++nt) {
#pragma unroll
            for (int kc = 0; kc < 4; ++kc) {
                bf16x8 bB = *(const bf16x8*)((const char*)&ldsW[nt * 16 + lrow][0] + kc * 64 + lq * 16);
                acc[nt] = MFMA16(aA[kc], bB, acc[nt]);
            }
        }
    }

#pragma unroll
    for (int nt = 0; nt < 8; ++nt) {
        if (TRANS) {
            int gm = m0 + w * 16 + lq * 4;       // j = 0 global row
            int b = gm >> 11, s = gm & 2047;
            int col = nt * 16 + lrow;            // o
            int kt = s >> 5, s32 = s & 31;
            int slot = (s32 >> 3) ^ ((col >> 1) & 3);
            bf16x4 y;
#pragma unroll
            for (int j = 0; j < 4; ++j) y[j] = (__bf16)(acc[nt][j] * outScale);
            *(bf16x4*)(out + (((size_t)b * 64 + kt) * 128 + col) * 32 + slot * 8 + (s32 & 7)) = y;
        } else {
#pragma unroll
            for (int j = 0; j < 4; ++j) {
                int gm = m0 + w * 16 + lq * 4 + j;
                int col = nt * 16 + lrow;
                out[(size_t)gm * 128 + col] = (__bf16)(acc[nt][j] * outScale);
            }
        }
    }
}

// value [8][2048][256] fp32 -> vt PACKED [b][kt=64][v=256][k=32] bf16,
// chunk-XOR baked: slot = ((k>>3) ^ ((v>>1)&3)).
__device__ __forceinline__ void vt_body(const float* __restrict__ V,
                                        __bf16* __restrict__ vt, int wg, char* smem) {
    auto tile = (__bf16(*)[72])smem;   // [64][72]
    const int t = threadIdx.x;
    const int b = wg >> 7, by = (wg >> 5) & 3, bxx = wg & 31;
    const int s0 = bxx * 64, v0 = by * 64;
#pragma unroll
    for (int i = 0; i < 4; ++i) {
        int idx = t + i * 256;
        int r = idx >> 4, c4 = idx & 15;
        float4 x = *(const float4*)(V + ((size_t)b * SEQ + s0 + r) * DV + v0 + c4 * 4);
        *(bf16x4*)&tile[r][c4 * 4] = cvt4(x);
    }
    __syncthreads();
#pragma unroll
    for (int i = 0; i < 4; ++i) {
        int idx = t + i * 256;
        int vv = idx >> 4, c4 = idx & 15;
        bf16x4 y;
        y[0] = tile[c4 * 4 + 0][vv]; y[1] = tile[c4 * 4 + 1][vv];
        y[2] = tile[c4 * 4 + 2][vv]; y[3] = tile[c4 * 4 + 3][vv];
        int v = v0 + vv;
        int kt = (s0 >> 5) + (c4 >> 3);
        int slot = ((c4 >> 1) & 3) ^ ((v >> 1) & 3);
        *(bf16x4*)(vt + (((size_t)b * 64 + kt) * 256 + v) * 32 + slot * 8 + (c4 & 1) * 4) = y;
    }
}

// ---------------------------------------------------------------------------
// k_pre: ALL independent producers in ONE launch (grid 1824, 3 wg/CU):
//   [0,256)    q-proj   -> r1s (pre-scaled 4.5)
//   [256,512)  k-proj   -> r2b
//   [512,768)  V-proj   -> r3t (packed, TRANS)
//   [768,1792) k_vt     -> vtb (packed)
//   [1792,..)  Wout cvt -> wob
// Heterogeneous co-residency hides the 1-wg/CU latency each had alone; 4
// launch gaps removed.
// ---------------------------------------------------------------------------
__global__ __launch_bounds__(256) void k_pre(const float* __restrict__ q,
                                             const float* __restrict__ k,
                                             const float* __restrict__ v,
                                             const float* __restrict__ W0,
                                             const float* __restrict__ W1,
                                             const float* __restrict__ W2,
                                             const float* __restrict__ Wout,
                                             __bf16* __restrict__ r1s,
                                             __bf16* __restrict__ r2b,
                                             __bf16* __restrict__ r3t,
                                             __bf16* __restrict__ vtb,
                                             __bf16* __restrict__ wob) {
    __shared__ __align__(16) char smem[52224];
    const int bx = blockIdx.x;
    if (bx < 256) {
        proj_body<128, 0>(q, W0, r1s, QK_SCALE, bx * 64, smem);
    } else if (bx < 512) {
        proj_body<128, 0>(k, W1, r2b, 1.0f, (bx - 256) * 64, smem);
    } else if (bx < 768) {
        proj_body<256, 1>(v, W2, r3t, 1.0f, (bx - 512) * 64, smem);
    } else if (bx < 1792) {
        vt_body(v, vtb, bx - 768, smem);
    } else {
        int i = (bx - 1792) * 256 + threadIdx.x;
        if (i < 8192) {
            float4 x = *(const float4*)(Wout + (size_t)i * 4);
            *(bf16x4*)(wob + (size_t)i * 4) = cvt4(x);
        }
    }
}

// ---------------------------------------------------------------------------
// Flash attention (unchanged from round 5 — split-K x2 + deferred sum)
// ---------------------------------------------------------------------------
__global__ __launch_bounds__(256) void k_flash(const __bf16* __restrict__ r1s,
                                               const __bf16* __restrict__ r2,
                                               const __bf16* __restrict__ r3p,
                                               __bf16* __restrict__ v1p,
                                               float* __restrict__ ml) {
    __shared__ __align__(16) __bf16 r2s[4][32 * 128];   // [kcol][d] rows 256B, s(r)=r&15
    __shared__ __align__(16) __bf16 r3s[4][128 * 32];   // [o][k]   rows  64B, s(r)=(r>>1)&3
    __shared__ __bf16 plds[4][16][48];                  // P C->A round-trip (wave-local)

    const int t = threadIdx.x;
    const int bx = (int)((blockIdx.x & 7) * 64 + (blockIdx.x >> 3));
    const int b = bx >> 6, rem = bx & 63, q0 = (rem >> 1) * 64, kh = rem & 1;
    const int w = t >> 6, l = t & 63, lrow = l & 15, lq = l >> 4;

    const __bf16* r1b = r1s + (size_t)b * SEQ * 128;
    const __bf16* r2b = r2 + (size_t)b * SEQ * 128 + (size_t)kh * 1024 * 128;
    const __bf16* r3b = r3p + (size_t)b * 64 * 128 * 32 + (size_t)kh * 32 * 128 * 32;

    bf16x8 aQ[4];
    {
        const __bf16* p = r1b + (size_t)(q0 + w * 16 + lrow) * 128 + lq * 8;
#pragma unroll
        for (int kc = 0; kc < 4; ++kc) aQ[kc] = *(const bf16x8*)(p + kc * 32);
    }

    const __bf16* p_r2[2];
    const __bf16* p_r3[2];
#pragma unroll
    for (int q1 = 0; q1 < 2; ++q1) {
        int r = 8 * w + 4 * q1 + (l >> 4);
        int c = (l & 15) ^ (r & 15);
        p_r2[q1] = r2b + (size_t)r * 128 + c * 8;
        p_r3[q1] = r3b + (size_t)(2 * w + q1) * 512 + l * 8;
    }

    auto stage = [&](int bi) {
#pragma unroll
        for (int q1 = 0; q1 < 2; ++q1) {
            gl_lds16(p_r2[q1], &r2s[bi][(2 * w + q1) * 512]);
            gl_lds16(p_r3[q1], &r3s[bi][(2 * w + q1) * 512]);
            p_r2[q1] += 32 * 128;
            p_r3[q1] += 128 * 32;
        }
    };

    f32x4 acc[8];
#pragma unroll
    for (int i = 0; i < 8; ++i) acc[i] = f32x4{0.f, 0.f, 0.f, 0.f};
    float mrow[4] = {-INFINITY, -INFINITY, -INFINITY, -INFINITY};
    float lsum[4] = {0.f, 0.f, 0.f, 0.f};   // per-lane partial (deferred reduction)

    stage(0); stage(1); stage(2);
    for (int it = 0; it < 32; ++it) {
        if (it < 30) { WAITV(8); } else if (it == 30) { WAITV(4); } else { WAITV(0); }
        __builtin_amdgcn_s_barrier();
        __builtin_amdgcn_sched_barrier(0);
        if (it + 3 < 32) stage((it + 3) & 3);
        __builtin_amdgcn_sched_barrier(0);
        const __bf16* R2 = &r2s[it & 3][0];
        const __bf16* R3 = &r3s[it & 3][0];

        f32x4 sc[2];
#pragma unroll
        for (int ct = 0; ct < 2; ++ct) {
            f32x4 s = f32x4{0.f, 0.f, 0.f, 0.f};
#pragma unroll
            for (int kc = 0; kc < 4; ++kc) {
                int p = (kc * 4 + lq) ^ lrow;
                bf16x8 bb = *(const bf16x8*)&R2[(ct * 16 + lrow) * 128 + p * 8];
                s = MFMA16(aQ[kc], bb, s);
            }
            sc[ct] = s;
        }

        float pm[4], al[4];
#pragma unroll
        for (int j = 0; j < 4; ++j) pm[j] = fmaxf(sc[0][j], sc[1][j]);
#pragma unroll
        for (int off = 1; off <= 8; off <<= 1)
#pragma unroll
            for (int j = 0; j < 4; ++j) pm[j] = fmaxf(pm[j], __shfl_xor(pm[j], off, 64));
#pragma unroll
        for (int j = 0; j < 4; ++j) {
            float mn = fmaxf(mrow[j], pm[j]);
            al[j] = __expf(mrow[j] - mn);
            mrow[j] = mn;
        }
        float pr[2][4];
#pragma unroll
        for (int ct = 0; ct < 2; ++ct)
#pragma unroll
            for (int j = 0; j < 4; ++j)
                pr[ct][j] = __expf(sc[ct][j] - mrow[j]);
#pragma unroll
        for (int j = 0; j < 4; ++j)
            lsum[j] = lsum[j] * al[j] + pr[0][j] + pr[1][j];
#pragma unroll
        for (int ot = 0; ot < 8; ++ot)
#pragma unroll
            for (int j = 0; j < 4; ++j) acc[ot][j] *= al[j];

#pragma unroll
        for (int ct = 0; ct < 2; ++ct)
#pragma unroll
            for (int j = 0; j < 4; ++j)
                plds[w][lq * 4 + j][ct * 16 + lrow] = (__bf16)pr[ct][j];
        __builtin_amdgcn_s_waitcnt(0xc07f);  // lgkmcnt(0) only — DMA stays in flight
        bf16x8 pA = *(const bf16x8*)&plds[w][lrow][lq * 8];

#pragma unroll
        for (int ot = 0; ot < 8; ++ot) {
            int p = lq ^ ((lrow >> 1) & 3);
            bf16x8 bb = *(const bf16x8*)&R3[(ot * 16 + lrow) * 32 + p * 8];
            acc[ot] = MFMA16(pA, bb, acc[ot]);
        }
    }

#pragma unroll
    for (int off = 1; off <= 8; off <<= 1)
#pragma unroll
        for (int j = 0; j < 4; ++j) lsum[j] += __shfl_xor(lsum[j], off, 64);

    __bf16* vp = v1p + (size_t)kh * 8 * SEQ * 128;
#pragma unroll
    for (int ot = 0; ot < 8; ++ot)
#pragma unroll
        for (int j = 0; j < 4; ++j) {
            int q = q0 + w * 16 + lq * 4 + j;
            float v = acc[ot][j] / lsum[j];
            vp[((size_t)b * SEQ + q) * 128 + ot * 16 + lrow] = (__bf16)v;
        }
    if (lrow == 0) {
#pragma unroll
        for (int j = 0; j < 4; ++j) {
            size_t row = (size_t)b * SEQ + q0 + w * 16 + lq * 4 + j;
            ml[((size_t)kh * 8 * SEQ + row) * 2 + 0] = mrow[j];
            ml[((size_t)kh * 8 * SEQ + row) * 2 + 1] = lsum[j];
        }
    }
}

// ---------------------------------------------------------------------------
// out = mask@value + (P@r3)@Wout^T.  v7: mask pipeline deepened to 3-iter
// slack (mbuf[4], issue epoch e+2, WAITV(3)) — Little's law on the HBM mask
// stream was the binding constraint (~13 B/cyc/CU with 1-iter slack).
// Split-K merge (ex-k_comb) folded inline into the epilogue. LDS 80 KB ->
// still 2 wg/CU.
// ---------------------------------------------------------------------------
__global__ __launch_bounds__(512, 4) void k_out(const float* __restrict__ mask,
                                                const __bf16* __restrict__ vtp,
                                                const __bf16* __restrict__ v1p,
                                                const float* __restrict__ ml,
                                                const __bf16* __restrict__ wob,
                                                float* __restrict__ out) {
    __shared__ __align__(16) __bf16 vbuf[3][256 * 32];  // 48 KB, slot-XOR baked
    __shared__ __align__(16) float mbuf[4][32 * 64];    // 32 KB, chunk-XOR baked

    const int t = threadIdx.x;
    const int bid = (int)((blockIdx.x & 7) * 64 + (blockIdx.x >> 3));  // XCD = batch
    const int m0 = bid * 32;
    const int b = m0 >> 11, q0 = m0 & 2047;
    const int w = t >> 6, l = t & 63, lrow = l & 15, lq = l >> 4;
    const int rg = w & 1, cg = w >> 1;   // 2 row-groups x 4 col-groups (64 v each)

    f32x4 acc[4];
#pragma unroll
    for (int i = 0; i < 4; ++i) acc[i] = f32x4{0.f, 0.f, 0.f, 0.f};

    // ---- staging pointers (role-split) ----
    const __bf16* vsrc[4];   // vt waves (w<4): 4 instrs/tile, 1 KB each, contiguous
    const float* msrc[2];    // mask waves (w>=4): 1 instr/iter, 3-iter slack
    if (w < 4) {
#pragma unroll
        for (int i = 0; i < 4; ++i)
            vsrc[i] = vtp + (size_t)b * 64 * 8192 + (w * 4 + i) * 512 + l * 8;
    } else {
        const int m = w - 4;
#pragma unroll
        for (int s = 0; s < 2; ++s) {
            int r = 4 * (m * 2 + s) + (l >> 4);
            int c = (l & 15) ^ (r & 7);
            msrc[s] = mask + ((size_t)(b * 2048 + q0 + r)) * 2048 + c * 4;
        }
    }

    // ---- prologue ----
    if (w < 4) {
#pragma unroll
        for (int kt = 0; kt < 2; ++kt)
#pragma unroll
            for (int i = 0; i < 4; ++i)
                gl_lds16(vsrc[i] + (size_t)kt * 8192, &vbuf[kt][(w * 4 + i) * 512]);
    } else {
        const int m = w - 4;
#pragma unroll
        for (int e = 0; e < 2; ++e)
#pragma unroll
            for (int s = 0; s < 2; ++s)
                gl_lds16(msrc[s] + (size_t)e * 64, &mbuf[e][(m * 2 + s) * 256]);
    }

    for (int it = 0; it < 64; ++it) {
        if (w >= 4) {
            const int m = w - 4;
            if (it <= 59) {
                int en = (it >> 1) + 2, s = it & 1;
                gl_lds16(msrc[s] + (size_t)en * 64, &mbuf[en & 3][(m * 2 + s) * 256]);
            }
            if ((it & 1) == 0) {
                if (it <= 58) { WAITV(3); } else if (it == 60) { WAITV(2); } else { WAITV(0); }
            }
        } else {
            if (it < 63) { WAITV(4); } else { WAITV(0); }
        }
        __builtin_amdgcn_s_barrier();
        __builtin_amdgcn_sched_barrier(0);
        if (w < 4 && it + 2 < 64) {
            int kt = it + 2;
#pragma unroll
            for (int i = 0; i < 4; ++i)
                gl_lds16(vsrc[i] + (size_t)kt * 8192, &vbuf[kt % 3][(w * 4 + i) * 512]);
        }
        __builtin_amdgcn_sched_barrier(0);

        // ---- compute (all 8 waves): 16q x 64v, BK=32 ----
        const float* Mb = &mbuf[(it >> 1) & 3][0];
        const __bf16* V = &vbuf[it % 3][0];
        const int h = it & 1;
        int c0 = (h * 8 + lq * 2) ^ (lrow & 7);
        int c1 = (h * 8 + lq * 2 + 1) ^ (lrow & 7);
        float4 f0 = *(const float4*)&Mb[(rg * 16 + lrow) * 64 + c0 * 4];
        float4 f1 = *(const float4*)&Mb[(rg * 16 + lrow) * 64 + c1 * 4];
        bf16x8 aM;
        aM[0] = (__bf16)f0.x; aM[1] = (__bf16)f0.y; aM[2] = (__bf16)f0.z; aM[3] = (__bf16)f0.w;
        aM[4] = (__bf16)f1.x; aM[5] = (__bf16)f1.y; aM[6] = (__bf16)f1.z; aM[7] = (__bf16)f1.w;

        const int pv = lq ^ ((lrow >> 1) & 3);
#pragma unroll
        for (int vt8 = 0; vt8 < 4; ++vt8) {
            bf16x8 bb = *(const bf16x8*)&V[(cg * 64 + vt8 * 16 + lrow) * 32 + pv * 8];
            acc[vt8] = MFMA16(aM, bb, acc[vt8]);
        }
    }

    // ---- epilogue: inline split-K merge (ex-k_comb, same math) + v1@Wout^T ----
    const int NROW = 8 * SEQ;
    const int row = m0 + rg * 16 + lrow;
    float am0 = ml[(size_t)row * 2 + 0], al0 = ml[(size_t)row * 2 + 1];
    float am1 = ml[((size_t)NROW + row) * 2 + 0], al1 = ml[((size_t)NROW + row) * 2 + 1];
    float M = fmaxf(am0, am1);
    float w0 = al0 * __expf(am0 - M), w1 = al1 * __expf(am1 - M);
    float inv = 1.f / (w0 + w1);
    w0 *= inv; w1 *= inv;
    bf16x8 aV[4];
#pragma unroll
    for (int oc = 0; oc < 4; ++oc) {
        bf16x8 a = *(const bf16x8*)(v1p + (size_t)row * 128 + oc * 32 + lq * 8);
        bf16x8 bh = *(const bf16x8*)(v1p + ((size_t)NROW + row) * 128 + oc * 32 + lq * 8);
        bf16x8 o;
#pragma unroll
        for (int j = 0; j < 8; ++j) o[j] = (__bf16)((float)a[j] * w0 + (float)bh[j] * w1);
        aV[oc] = o;
    }
#pragma unroll
    for (int vt8 = 0; vt8 < 4; ++vt8) {
#pragma unroll
        for (int oc = 0; oc < 4; ++oc) {
            bf16x8 bb = *(const bf16x8*)(wob + (size_t)(cg * 64 + vt8 * 16 + lrow) * 128 + oc * 32 + lq * 8);
            acc[vt8] = MFMA16(aV[oc], bb, acc[vt8]);
        }
    }

#pragma unroll
    for (int vt8 = 0; vt8 < 4; ++vt8)
#pragma unroll
        for (int j = 0; j < 4; ++j) {
            int gq = m0 + rg * 16 + lq * 4 + j;
            out[(size_t)gq * 256 + cg * 64 + vt8 * 16 + lrow] = acc[vt8][j];
        }
}

// ---------------------------------------------------------------------------
extern "C" void kernel_launch(void* const* d_in, const int* in_sizes, int n_in,
                              void* d_out, int out_size, void* d_ws, size_t ws_size,
                              hipStream_t stream) {
    const float* q    = (const float*)d_in[0];
    const float* k    = (const float*)d_in[1];
    const float* v    = (const float*)d_in[2];
    const float* mask = (const float*)d_in[3];
    const float* W0   = (const float*)d_in[4];
    const float* W1   = (const float*)d_in[5];
    const float* W2   = (const float*)d_in[6];
    const float* Wout = (const float*)d_in[7];
    float* out = (float*)d_out;

    char* ws = (char*)d_ws;
    __bf16* r1s = (__bf16*)(ws);                  // [8][2048][128] bf16 (pre-scaled 4.5)
    __bf16* r2b = (__bf16*)(ws + (4ull << 20));   // [8][2048][128] bf16
    __bf16* r3t = (__bf16*)(ws + (8ull << 20));   // [8][64][128][32] bf16 PACKED
    __bf16* vtb = (__bf16*)(ws + (12ull << 20));  // [8][64][256][32] bf16 PACKED
    __bf16* wob = (__bf16*)(ws + (20ull << 20));  // [256][128] bf16
    __bf16* v1p = (__bf16*)(ws + (25ull << 20));  // [2][8][2048][128] bf16 partials
    float*  mlb = (float*)(ws + (33ull << 20));   // [2][8*2048][2] f32 (m, l)

    k_pre<<<1824, 256, 0, stream>>>(q, k, v, W0, W1, W2, Wout, r1s, r2b, r3t, vtb, wob);
    k_flash<<<512, 256, 0, stream>>>(r1s, r2b, r3t, v1p, mlb);
    k_out<<<512, 512, 0, stream>>>(mask, vtb, v1p, mlb, wob, out);
}